// Round 4
// baseline (604.271 us; speedup 1.0000x reference)
//
#include <hip/hip_runtime.h>
#include <hip/hip_bf16.h>
#include <cstdint>
#include <cstddef>

typedef __attribute__((ext_vector_type(8))) short short8;
typedef __attribute__((ext_vector_type(4))) float f32x4;
typedef unsigned short u16;

static __device__ __forceinline__ u16 f2bf(float f) {
  __hip_bfloat16 h = __float2bfloat16(f);
  return *reinterpret_cast<u16*>(&h);
}

static __device__ __forceinline__ void gload16(const void* g, void* l) {
  __builtin_amdgcn_global_load_lds(
      (const __attribute__((address_space(1))) void*)g,
      (__attribute__((address_space(3))) void*)l, 16, 0, 0);
}

// ---------------- prep kernels ----------------

__global__ void cast_k(const float* __restrict__ in, u16* __restrict__ out, int n4) {
  int i = blockIdx.x * 256 + threadIdx.x;
  if (i < n4) {
    float4 v = ((const float4*)in)[i];
    union { u16 u[4]; uint2 p; } r;
    r.u[0] = f2bf(v.x); r.u[1] = f2bf(v.y); r.u[2] = f2bf(v.z); r.u[3] = f2bf(v.w);
    ((uint2*)out)[i] = r.p;
  }
}

// in_t[b][s][i] = bf16( concat(x1,x2)[b][i][s] ), i in [0,2048)
__global__ void build_int(const float* __restrict__ x1, const float* __restrict__ x2,
                          u16* __restrict__ in_t) {
  __shared__ float tile[64][65];
  const int it = blockIdx.x;   // 32 i-tiles
  const int st = blockIdx.y;   // 16 s-tiles
  const int b  = blockIdx.z;   // 8
  const int i0 = it * 64, s0 = st * 64;
  const float* src = (i0 < 1024)
      ? x1 + ((size_t)b * 1024 + i0) * 1024
      : x2 + ((size_t)b * 1024 + (i0 - 1024)) * 1024;
  const int t = threadIdx.x;
  #pragma unroll
  for (int jj = 0; jj < 16; ++jj) {
    int idx = jj * 256 + t;
    int ii = idx >> 6, si = idx & 63;
    tile[ii][si] = src[(size_t)ii * 1024 + s0 + si];
  }
  __syncthreads();
  #pragma unroll
  for (int jj = 0; jj < 16; ++jj) {
    int idx = jj * 256 + t;
    int si = idx >> 6, ii = idx & 63;
    in_t[((size_t)b * 1024 + s0 + si) * 2048 + i0 + ii] = f2bf(tile[ii][si]);
  }
}

// Wp[q][o][i] = bf16( conv_w[o][i][q] ),  q = ky*3+kx
__global__ void pack_wp(const float* __restrict__ cw, u16* __restrict__ Wp) {
  __shared__ float sb[2304];
  const int blk = blockIdx.x;  // 8192
  const int t = threadIdx.x;   // 256
  const size_t base = (size_t)blk * 2304;
  #pragma unroll
  for (int jj = 0; jj < 9; ++jj) sb[jj * 256 + t] = cw[base + jj * 256 + t];
  __syncthreads();
  const int p = blk * 256 + t;  // (o,i) linear
  #pragma unroll
  for (int q = 0; q < 9; ++q)
    Wp[(size_t)q * 2097152 + p] = f2bf(sb[t * 9 + q]);
}

__global__ void zero_k(u16* z) { z[threadIdx.x] = 0; }

// ---------------- phased GEMM (C = A @ B^T), 256x128 tile, BK=64 ----------------
// 512 threads = 8 waves (4M x 2N), wave tile 64x64. Triple-buffered LDS (144 KiB).
// m201-style schedule: 2 sub-phases per K-tile, each {8 ds_read_b128; 3 gload
// issues; s_barrier; lgkmcnt(0)+sched_barrier; setprio 16xMFMA; s_barrier}.
// Counted vmcnt(6) once per K-tile (T4); T2 swizzle; T5 setprio; T1 XCD chunking.

enum { GM_PLAIN = 0, GM_VT = 1, GM_PROJ = 2, GM_CONV = 3, GM_KV = 4 };

template<int MODE>
__global__ __launch_bounds__(512, 2)
void gemm4_k(const u16* __restrict__ A, const u16* __restrict__ B,
             u16* __restrict__ Cb, u16* __restrict__ Cb2, float* __restrict__ Cf,
             const float* __restrict__ bias, const float* __restrict__ resid,
             const u16* __restrict__ zb, int Ktot, int ntn_sh) {
  // per buffer: A 256x64 (16384 u16) + B 128x64 (8192 u16) = 48 KB
  __shared__ u16 lds[3 * 24576];
  const int tid = threadIdx.x;
  const int lane = tid & 63;
  const int w = tid >> 6;
  const int l15 = lane & 15, l4 = lane >> 4;

  // T1: chunked XCD remap (nwg % 8 == 0 -> bijective)
  const int nwg = gridDim.x;
  const int bid = blockIdx.x;
  const int lb = (bid & 7) * (nwg >> 3) + (bid >> 3);
  const int tm = lb >> ntn_sh;
  const int tn = lb & ((1 << ntn_sh) - 1);
  const int row0 = tm * 256, col0 = tn * 128;
  const int wr = (w >> 1) * 64, wc = (w & 1) * 64;

  // staging geometry: sweep u covers row u*64 + sr; granule pp inverse-swizzled
  const int sr = w * 8 + (lane >> 3);
  const int pp = (lane & 7) ^ (lane >> 3);

  int am[4], ay[4], ax[4];
  #pragma unroll
  for (int u = 0; u < 4; ++u) {
    const int m = row0 + u * 64 + sr;
    am[u] = m;
    const int s = m & 1023;
    ay[u] = s >> 5; ax[u] = s & 31;
  }

  f32x4 acc[4][4];
  #pragma unroll
  for (int i = 0; i < 4; ++i)
    #pragma unroll
    for (int jj = 0; jj < 4; ++jj)
      acc[i][jj] = (f32x4){0.f, 0.f, 0.f, 0.f};

  const int nK = Ktot >> 6;

  // phase A staging: A-rows u=0,1,2 (3 gloads)
  auto stageA = [&](int kt, u16* buf) {
    u16* da = buf + (size_t)w * 512;
    if constexpr (MODE == GM_CONV) {
      const int q = kt >> 5;
      const int ks0 = (kt & 31) << 6;
      const int qd = (q >= 6) ? 2 : (q >= 3) ? 1 : 0;
      const int dy = qd - 1, dx = q - qd * 3 - 1;
      const int dd = (dy << 5) + dx;
      #pragma unroll
      for (int u = 0; u < 3; ++u) {
        const int yy = ay[u] + dy, xx = ax[u] + dx;
        const bool valid = ((unsigned)yy < 32u) && ((unsigned)xx < 32u);
        const u16* ga = valid ? A + (((size_t)(am[u] + dd)) << 11) + ks0 + pp * 8 : zb;
        gload16(ga, da + u * 4096);
      }
    } else {
      const int k0 = kt << 6;
      #pragma unroll
      for (int u = 0; u < 3; ++u) {
        const u16* ga = A + (size_t)(row0 + u * 64 + sr) * Ktot + k0 + pp * 8;
        gload16(ga, da + u * 4096);
      }
    }
  };
  // phase B staging: A-row u=3 + B-rows u=0,1 (3 gloads)
  auto stageB = [&](int kt, u16* buf) {
    u16* da = buf + (size_t)w * 512;
    u16* db = buf + 16384 + (size_t)w * 512;
    if constexpr (MODE == GM_CONV) {
      const int q = kt >> 5;
      const int ks0 = (kt & 31) << 6;
      const int qd = (q >= 6) ? 2 : (q >= 3) ? 1 : 0;
      const int dy = qd - 1, dx = q - qd * 3 - 1;
      const int dd = (dy << 5) + dx;
      {
        const int yy = ay[3] + dy, xx = ax[3] + dx;
        const bool valid = ((unsigned)yy < 32u) && ((unsigned)xx < 32u);
        const u16* ga = valid ? A + (((size_t)(am[3] + dd)) << 11) + ks0 + pp * 8 : zb;
        gload16(ga, da + 3 * 4096);
      }
      const size_t boff = ((size_t)q << 21) + ks0 + pp * 8;
      #pragma unroll
      for (int u = 0; u < 2; ++u) {
        const u16* gb = B + boff + ((size_t)(col0 + u * 64 + sr) << 11);
        gload16(gb, db + u * 4096);
      }
    } else {
      const int k0 = kt << 6;
      {
        const u16* ga = A + (size_t)(row0 + 3 * 64 + sr) * Ktot + k0 + pp * 8;
        gload16(ga, da + 3 * 4096);
      }
      #pragma unroll
      for (int u = 0; u < 2; ++u) {
        const u16* gb = B + (size_t)(col0 + u * 64 + sr) * Ktot + k0 + pp * 8;
        gload16(gb, db + u * 4096);
      }
    }
  };

  u16* pb0 = lds;
  u16* pb1 = lds + 24576;
  u16* pb2 = lds + 49152;

  stageA(0, pb0); stageB(0, pb0);
  stageA(1, pb1); stageB(1, pb1);
  asm volatile("s_waitcnt vmcnt(6)" ::: "memory");
  __builtin_amdgcn_s_barrier();

  for (int t = 0; t < nK; ++t) {
    const char* Ar = (const char*)pb0;
    const char* Br = (const char*)(pb0 + 16384);
    // ---------- phase A (ks=0) ----------
    {
      const int bcol = (l4 << 4) ^ ((l15 & 7) << 4);
      short8 av[4], bv[4];
      #pragma unroll
      for (int mi = 0; mi < 4; ++mi)
        av[mi] = *(const short8*)(Ar + (wr + mi * 16 + l15) * 128 + bcol);
      #pragma unroll
      for (int ni = 0; ni < 4; ++ni)
        bv[ni] = *(const short8*)(Br + (wc + ni * 16 + l15) * 128 + bcol);
      if (t + 2 < nK) stageA(t + 2, pb2);
      __builtin_amdgcn_s_barrier();
      asm volatile("s_waitcnt lgkmcnt(0)" ::: "memory");
      __builtin_amdgcn_sched_barrier(0);
      __builtin_amdgcn_s_setprio(1);
      #pragma unroll
      for (int mi = 0; mi < 4; ++mi)
        #pragma unroll
        for (int ni = 0; ni < 4; ++ni)
          acc[mi][ni] = __builtin_amdgcn_mfma_f32_16x16x32_bf16(av[mi], bv[ni], acc[mi][ni], 0, 0, 0);
      __builtin_amdgcn_s_setprio(0);
      __builtin_amdgcn_s_barrier();
    }
    // ---------- phase B (ks=1) ----------
    {
      const int bcol = (64 + (l4 << 4)) ^ ((l15 & 7) << 4);
      short8 av[4], bv[4];
      #pragma unroll
      for (int mi = 0; mi < 4; ++mi)
        av[mi] = *(const short8*)(Ar + (wr + mi * 16 + l15) * 128 + bcol);
      #pragma unroll
      for (int ni = 0; ni < 4; ++ni)
        bv[ni] = *(const short8*)(Br + (wc + ni * 16 + l15) * 128 + bcol);
      if (t + 2 < nK) {
        stageB(t + 2, pb2);
        asm volatile("s_waitcnt vmcnt(6)" ::: "memory");
      } else if (t + 1 < nK) {
        asm volatile("s_waitcnt vmcnt(0)" ::: "memory");
      }
      __builtin_amdgcn_s_barrier();
      asm volatile("s_waitcnt lgkmcnt(0)" ::: "memory");
      __builtin_amdgcn_sched_barrier(0);
      __builtin_amdgcn_s_setprio(1);
      #pragma unroll
      for (int mi = 0; mi < 4; ++mi)
        #pragma unroll
        for (int ni = 0; ni < 4; ++ni)
          acc[mi][ni] = __builtin_amdgcn_mfma_f32_16x16x32_bf16(av[mi], bv[ni], acc[mi][ni], 0, 0, 0);
      __builtin_amdgcn_s_setprio(0);
      __builtin_amdgcn_s_barrier();
    }
    u16* tmp = pb0; pb0 = pb1; pb1 = pb2; pb2 = tmp;
  }

  // epilogue: D layout col=lane&15, row=(lane>>4)*4+j
  #pragma unroll
  for (int mi = 0; mi < 4; ++mi) {
    #pragma unroll
    for (int ni = 0; ni < 4; ++ni) {
      #pragma unroll
      for (int j = 0; j < 4; ++j) {
        const int grow = row0 + wr + mi * 16 + l4 * 4 + j;
        const int gcol = col0 + wc + ni * 16 + l15;
        const float v = acc[mi][ni][j];
        if constexpr (MODE == GM_PLAIN) {
          Cb[((size_t)grow << 10) + gcol] = f2bf(v);
        } else if constexpr (MODE == GM_VT) {
          const int b = grow >> 10, ms = grow & 1023;
          const int h = gcol >> 7, d = gcol & 127;
          Cb[((size_t)((b * 8 + h) * 128 + d) << 10) + ms] = f2bf(v);
        } else if constexpr (MODE == GM_KV) {
          if (gcol < 1024) {
            Cb[((size_t)grow << 10) + gcol] = f2bf(v);
          } else {
            const int c = gcol - 1024;
            const int b = grow >> 10, ms = grow & 1023;
            const int h = c >> 7, d = c & 127;
            Cb2[((size_t)((b * 8 + h) * 128 + d) << 10) + ms] = f2bf(v);
          }
        } else if constexpr (MODE == GM_PROJ) {
          const size_t o = ((size_t)grow << 10) + gcol;
          Cf[o] = v + bias[gcol] + resid[o];
        } else {  // GM_CONV: xc[b][o][s]
          const int b = grow >> 10, s = grow & 1023;
          Cb[((size_t)((b << 10) + gcol) << 10) + s] = f2bf(v + bias[gcol]);
        }
      }
    }
  }
}

// ---------------- flash attention (double-buffered, 1 barrier/iter) ----------------
// grid (16 mtiles, 64 bh). 4 waves; wave w owns Q rows [w*16, w*16+16).
// K/V LDS granule-XOR swizzled (T2): stage fetches global granule g^(r&7) into
// linear LDS granule g; reads XOR col with (row&7).
__global__ __launch_bounds__(256, 2)
void attn2_k(const u16* __restrict__ Q, const u16* __restrict__ K,
             const u16* __restrict__ Vt, u16* __restrict__ O) {
  __shared__ u16 Ks[2][64 * 128];
  __shared__ u16 Vs[2][128 * 64];
  __shared__ u16 Plds[4][16 * 80];
  const int mtile = blockIdx.x;
  const int bh = blockIdx.y;
  const int b = bh >> 3, h = bh & 7;
  const int tid = threadIdx.x, lane = tid & 63, w = tid >> 6;
  const int l15 = lane & 15, l4 = lane >> 4;

  short8 qf[4];
  {
    const int qrow = b * 1024 + mtile * 64 + w * 16 + l15;
    const u16* qb = Q + ((size_t)qrow << 10) + h * 128;
    #pragma unroll
    for (int kk = 0; kk < 4; ++kk)
      qf[kk] = *(const short8*)(qb + kk * 32 + l4 * 8);
  }

  f32x4 o[8];
  #pragma unroll
  for (int db = 0; db < 8; ++db) o[db] = (f32x4){0.f, 0.f, 0.f, 0.f};
  float mrow[4], lrow[4];
  #pragma unroll
  for (int j = 0; j < 4; ++j) { mrow[j] = -1e30f; lrow[j] = 0.f; }
  const float scale = 0.08838834764831845f;  // 128^-0.5

  auto stageKV = [&](int kt, int half) {
    #pragma unroll
    for (int j = 0; j < 4; ++j) {
      const int c = (j * 4 + w) * 64 + lane;
      const int r = c >> 4;
      const int coff = (((c & 15) ^ (r & 7)) << 3);
      const u16* gp = K + ((size_t)(b * 1024 + kt * 64 + r) << 10) + h * 128 + coff;
      gload16(gp, (void*)(Ks[half] + (j * 4 + w) * 512));
    }
    #pragma unroll
    for (int j = 0; j < 4; ++j) {
      const int c = (j * 4 + w) * 64 + lane;
      const int r = c >> 3;
      const int coff = (((c & 7) ^ (r & 7)) << 3);
      const u16* gp = Vt + ((size_t)((b * 8 + h) * 128 + r) << 10) + kt * 64 + coff;
      gload16(gp, (void*)(Vs[half] + (j * 4 + w) * 512));
    }
  };

  stageKV(0, 0);
  for (int kt = 0; kt < 16; ++kt) {
    const int cur = kt & 1;
    asm volatile("s_waitcnt vmcnt(0)" ::: "memory");
    __builtin_amdgcn_s_barrier();
    if (kt + 1 < 16) stageKV(kt + 1, cur ^ 1);

    const u16* ks_ = Ks[cur];
    const u16* vs_ = Vs[cur];
    // S = Q K^T  (wave's 16 rows x 64 cols)
    f32x4 s[4];
    #pragma unroll
    for (int cb = 0; cb < 4; ++cb) {
      s[cb] = (f32x4){0.f, 0.f, 0.f, 0.f};
      #pragma unroll
      for (int kk = 0; kk < 4; ++kk) {
        const int col = (kk * 32 + l4 * 8) ^ ((l15 & 7) << 3);
        short8 bK = *(const short8*)(ks_ + (cb * 16 + l15) * 128 + col);
        s[cb] = __builtin_amdgcn_mfma_f32_16x16x32_bf16(qf[kk], bK, s[cb], 0, 0, 0);
      }
    }
    #pragma unroll
    for (int cb = 0; cb < 4; ++cb) {
      s[cb][0] *= scale; s[cb][1] *= scale; s[cb][2] *= scale; s[cb][3] *= scale;
    }
    // online softmax per row j (row = l4*4+j; reduce across the 16 lanes l15)
    #pragma unroll
    for (int j = 0; j < 4; ++j) {
      float mx = fmaxf(fmaxf(s[0][j], s[1][j]), fmaxf(s[2][j], s[3][j]));
      #pragma unroll
      for (int off = 8; off >= 1; off >>= 1)
        mx = fmaxf(mx, __shfl_xor(mx, off, 64));
      const float mn = fmaxf(mrow[j], mx);
      const float fac = __expf(mrow[j] - mn);
      mrow[j] = mn;
      float rs = 0.f;
      #pragma unroll
      for (int cb = 0; cb < 4; ++cb) {
        const float p = __expf(s[cb][j] - mn);
        s[cb][j] = p;
        rs += p;
      }
      #pragma unroll
      for (int off = 8; off >= 1; off >>= 1)
        rs += __shfl_xor(rs, off, 64);
      lrow[j] = lrow[j] * fac + rs;
      #pragma unroll
      for (int db = 0; db < 8; ++db) o[db][j] *= fac;
    }
    // P -> per-wave LDS (no cross-wave barrier needed)
    u16* pl = Plds[w];
    #pragma unroll
    for (int cb = 0; cb < 4; ++cb)
      #pragma unroll
      for (int j = 0; j < 4; ++j)
        pl[(l4 * 4 + j) * 80 + cb * 16 + l15] = f2bf(s[cb][j]);
    asm volatile("s_waitcnt lgkmcnt(0)" ::: "memory");
    __builtin_amdgcn_sched_barrier(0);
    short8 ap[2];
    #pragma unroll
    for (int ks2 = 0; ks2 < 2; ++ks2)
      ap[ks2] = *(const short8*)(pl + l15 * 80 + ks2 * 32 + l4 * 8);
    #pragma unroll
    for (int db = 0; db < 8; ++db) {
      #pragma unroll
      for (int ks2 = 0; ks2 < 2; ++ks2) {
        const int col = (ks2 * 32 + l4 * 8) ^ ((l15 & 7) << 3);
        short8 bV = *(const short8*)(vs_ + (db * 16 + l15) * 64 + col);
        o[db] = __builtin_amdgcn_mfma_f32_16x16x32_bf16(ap[ks2], bV, o[db], 0, 0, 0);
      }
    }
  }
  #pragma unroll
  for (int db = 0; db < 8; ++db) {
    #pragma unroll
    for (int j = 0; j < 4; ++j) {
      const int grow = b * 1024 + mtile * 64 + w * 16 + l4 * 4 + j;
      const int gcol = h * 128 + db * 16 + l15;
      O[((size_t)grow << 10) + gcol] = f2bf(o[db][j] / lrow[j]);
    }
  }
}

// ---------------- launch ----------------

extern "C" void kernel_launch(void* const* d_in, const int* in_sizes, int n_in,
                              void* d_out, int out_size, void* d_ws, size_t ws_size,
                              hipStream_t stream) {
  const float* x1     = (const float*)d_in[0];
  const float* x2     = (const float*)d_in[1];
  const float* conv_w = (const float*)d_in[2];
  const float* conv_b = (const float*)d_in[3];
  const float* wq     = (const float*)d_in[4];
  const float* wk     = (const float*)d_in[5];
  const float* wv     = (const float*)d_in[6];
  const float* proj_w = (const float*)d_in[7];
  const float* proj_b = (const float*)d_in[8];
  float* out = (float*)d_out;

  char* ws = (char*)d_ws;
  size_t off = 0;
  auto alloc = [&](size_t bytes) -> void* {
    void* p = ws + off;
    off += (bytes + 255) & ~(size_t)255;
    return p;
  };
  u16* x1b  = (u16*)alloc(8192ULL * 1024 * 2);
  u16* in_t = (u16*)alloc(8ULL * 1024 * 2048 * 2);
  u16* Wp   = (u16*)alloc(9ULL * 2097152 * 2);
  u16* wqb  = (u16*)alloc(1048576ULL * 2);
  u16* wkb  = (u16*)alloc(1048576ULL * 2);  // contiguous with wvb -> fused KV B
  u16* wvb  = (u16*)alloc(1048576ULL * 2);
  u16* pjb  = (u16*)alloc(1048576ULL * 2);
  u16* xc   = (u16*)alloc(8192ULL * 1024 * 2);
  u16* Qb   = (u16*)alloc(8192ULL * 1024 * 2);
  u16* Kb   = (u16*)alloc(8192ULL * 1024 * 2);
  u16* Vtb  = (u16*)alloc(8192ULL * 1024 * 2);
  u16* Ob   = (u16*)alloc(8192ULL * 1024 * 2);
  u16* zb   = (u16*)alloc(256);

  // prep
  cast_k<<<8192, 256, 0, stream>>>(x1, x1b, 2097152);
  cast_k<<<1024, 256, 0, stream>>>(wq, wqb, 262144);
  cast_k<<<1024, 256, 0, stream>>>(wk, wkb, 262144);
  cast_k<<<1024, 256, 0, stream>>>(wv, wvb, 262144);
  cast_k<<<1024, 256, 0, stream>>>(proj_w, pjb, 262144);
  build_int<<<dim3(32, 16, 8), 256, 0, stream>>>(x1, x2, in_t);
  pack_wp<<<8192, 256, 0, stream>>>(conv_w, Wp);
  zero_k<<<1, 128, 0, stream>>>(zb);

  // conv as implicit GEMM (9 shifted planes over K=18432)
  gemm4_k<GM_CONV><<<256, 512, 0, stream>>>(in_t, Wp, xc, nullptr, nullptr, conv_b, nullptr, zb, 18432, 3);
  // Q
  gemm4_k<GM_PLAIN><<<256, 512, 0, stream>>>(x1b, wqb, Qb, nullptr, nullptr, nullptr, nullptr, zb, 1024, 3);
  // fused K+V (B = [wk;wv] contiguous, N=2048)
  gemm4_k<GM_KV><<<512, 512, 0, stream>>>(xc, wkb, Kb, Vtb, nullptr, nullptr, nullptr, zb, 1024, 4);
  // attention
  attn2_k<<<dim3(16, 64), 256, 0, stream>>>(Qb, Kb, Vtb, Ob);
  // projection + bias + residual (f32 out)
  gemm4_k<GM_PROJ><<<256, 512, 0, stream>>>(Ob, pjb, nullptr, nullptr, out, proj_b, x1, zb, 1024, 3);
}

// Round 5
// 588.172 us; speedup vs baseline: 1.0274x; 1.0274x over previous
//
#include <hip/hip_runtime.h>
#include <hip/hip_bf16.h>
#include <cstdint>
#include <cstddef>

typedef __attribute__((ext_vector_type(8))) short short8;
typedef __attribute__((ext_vector_type(4))) float f32x4;
typedef unsigned short u16;

static __device__ __forceinline__ u16 f2bf(float f) {
  __hip_bfloat16 h = __float2bfloat16(f);
  return *reinterpret_cast<u16*>(&h);
}

static __device__ __forceinline__ void gload16(const void* g, void* l) {
  __builtin_amdgcn_global_load_lds(
      (const __attribute__((address_space(1))) void*)g,
      (__attribute__((address_space(3))) void*)l, 16, 0, 0);
}

// ---------------- prep kernels ----------------

// all four weight casts in one dispatch
__global__ void cast4_k(const float* __restrict__ a, const float* __restrict__ b,
                        const float* __restrict__ c, const float* __restrict__ d,
                        u16* __restrict__ oa, u16* __restrict__ ob,
                        u16* __restrict__ oc, u16* __restrict__ od) {
  const int which = blockIdx.y;
  const float* src = (which == 0) ? a : (which == 1) ? b : (which == 2) ? c : d;
  u16* dst = (which == 0) ? oa : (which == 1) ? ob : (which == 2) ? oc : od;
  int i = blockIdx.x * 256 + threadIdx.x;   // 262144 float4 per tensor
  float4 v = ((const float4*)src)[i];
  union { u16 u[4]; uint2 p; } r;
  r.u[0] = f2bf(v.x); r.u[1] = f2bf(v.y); r.u[2] = f2bf(v.z); r.u[3] = f2bf(v.w);
  ((uint2*)dst)[i] = r.p;
}

// in_t[b][s][i] = bf16( concat(x1,x2)[b][i][s] );  also emits x1b = bf16(x1) flat
__global__ void build_int2(const float* __restrict__ x1, const float* __restrict__ x2,
                           u16* __restrict__ in_t, u16* __restrict__ x1b) {
  __shared__ float tile[64][65];
  const int it = blockIdx.x;   // 32 i-tiles
  const int st = blockIdx.y;   // 16 s-tiles
  const int b  = blockIdx.z;   // 8
  const int i0 = it * 64, s0 = st * 64;
  const bool isx1 = (i0 < 1024);
  const float* src = isx1
      ? x1 + ((size_t)b * 1024 + i0) * 1024
      : x2 + ((size_t)b * 1024 + (i0 - 1024)) * 1024;
  const int t = threadIdx.x;
  #pragma unroll
  for (int jj = 0; jj < 16; ++jj) {
    int idx = jj * 256 + t;
    int ii = idx >> 6, si = idx & 63;
    float v = src[(size_t)ii * 1024 + s0 + si];
    tile[ii][si] = v;
    if (isx1)
      x1b[((size_t)b * 1024 + i0 + ii) * 1024 + s0 + si] = f2bf(v);
  }
  __syncthreads();
  #pragma unroll
  for (int jj = 0; jj < 16; ++jj) {
    int idx = jj * 256 + t;
    int si = idx >> 6, ii = idx & 63;
    in_t[((size_t)b * 1024 + s0 + si) * 2048 + i0 + ii] = f2bf(tile[ii][si]);
  }
}

// Wp[q][o][i] = bf16( conv_w[o][i][q] ),  q = ky*3+kx
__global__ void pack_wp(const float* __restrict__ cw, u16* __restrict__ Wp) {
  __shared__ float sb[2304];
  const int blk = blockIdx.x;  // 8192
  const int t = threadIdx.x;   // 256
  const size_t base = (size_t)blk * 2304;
  #pragma unroll
  for (int jj = 0; jj < 9; ++jj) sb[jj * 256 + t] = cw[base + jj * 256 + t];
  __syncthreads();
  const int p = blk * 256 + t;  // (o,i) linear
  #pragma unroll
  for (int q = 0; q < 9; ++q)
    Wp[(size_t)q * 2097152 + p] = f2bf(sb[t * 9 + q]);
}

__global__ void zero_k(u16* z) { z[threadIdx.x] = 0; }

// split-K combine: xc[b][o][s] = bf16(p0 + p1 + bias[o]); p is [kz][b*1024+s][o] f32
__global__ void addc_k(const float* __restrict__ p, const float* __restrict__ bias,
                       u16* __restrict__ xc) {
  __shared__ float tile[64][65];
  const int st = blockIdx.x;   // 16 s-tiles
  const int ot = blockIdx.y;   // 16 o-tiles
  const int b  = blockIdx.z;   // 8
  const int s0 = st * 64, o0 = ot * 64;
  const int t = threadIdx.x;
  const float* p1 = p + 8388608;
  #pragma unroll
  for (int jj = 0; jj < 16; ++jj) {
    int idx = jj * 256 + t;
    int si = idx >> 6, oi = idx & 63;
    const size_t m = ((size_t)b * 1024 + s0 + si) * 1024 + o0 + oi;
    tile[si][oi] = p[m] + p1[m] + bias[o0 + oi];
  }
  __syncthreads();
  #pragma unroll
  for (int jj = 0; jj < 16; ++jj) {
    int idx = jj * 256 + t;
    int oi = idx >> 6, si = idx & 63;
    xc[((size_t)b * 1024 + o0 + oi) * 1024 + s0 + si] = f2bf(tile[si][oi]);
  }
}

enum { GM_PLAIN = 0, GM_VT = 1, GM_PROJ = 2, GM_CONV = 3, GM_KV = 4 };

// ---------------- GEMM A: 256x128 tile, BK=64, triple-buffer 144KB (round-3 915TF)
// for grid-256 GEMMs (Q, proj) where 2 blocks/CU is unreachable anyway.
template<int MODE>
__global__ __launch_bounds__(512, 2)
void gemm3_k(const u16* __restrict__ A, const u16* __restrict__ B,
             u16* __restrict__ Cb, float* __restrict__ Cf,
             const float* __restrict__ bias, const float* __restrict__ resid,
             int Ktot, int ntn_sh) {
  __shared__ u16 lds[3 * 24576];
  const int tid = threadIdx.x;
  const int lane = tid & 63;
  const int w = tid >> 6;
  const int l15 = lane & 15, l4 = lane >> 4;

  const int nwg = gridDim.x;
  const int bid = blockIdx.x;
  const int lb = (bid & 7) * (nwg >> 3) + (bid >> 3);
  const int tm = lb >> ntn_sh;
  const int tn = lb & ((1 << ntn_sh) - 1);
  const int row0 = tm * 256, col0 = tn * 128;
  const int wr = (w >> 1) * 64, wc = (w & 1) * 64;

  const int sr = w * 8 + (lane >> 3);
  const int pp = (lane & 7) ^ (lane >> 3);

  f32x4 acc[4][4];
  #pragma unroll
  for (int i = 0; i < 4; ++i)
    #pragma unroll
    for (int jj = 0; jj < 4; ++jj)
      acc[i][jj] = (f32x4){0.f, 0.f, 0.f, 0.f};

  const int nK = Ktot >> 6;

  auto stage = [&](int kt, u16* buf) {
    u16* da = buf + (size_t)w * 512;
    u16* db = buf + 16384 + (size_t)w * 512;
    const int k0 = kt << 6;
    #pragma unroll
    for (int u = 0; u < 4; ++u) {
      const u16* ga = A + (size_t)(row0 + u * 64 + sr) * Ktot + k0 + pp * 8;
      gload16(ga, da + u * 4096);
    }
    #pragma unroll
    for (int u = 0; u < 2; ++u) {
      const u16* gb = B + (size_t)(col0 + u * 64 + sr) * Ktot + k0 + pp * 8;
      gload16(gb, db + u * 4096);
    }
  };

  auto compute = [&](const u16* buf) {
    const char* Ar = (const char*)buf;
    const char* Br = (const char*)(buf + 16384);
    #pragma unroll
    for (int ks = 0; ks < 2; ++ks) {
      const int bcol = ((ks << 6) + (l4 << 4)) ^ ((l15 & 7) << 4);
      short8 av[4], bv[4];
      #pragma unroll
      for (int mi = 0; mi < 4; ++mi)
        av[mi] = *(const short8*)(Ar + (wr + mi * 16 + l15) * 128 + bcol);
      #pragma unroll
      for (int ni = 0; ni < 4; ++ni)
        bv[ni] = *(const short8*)(Br + (wc + ni * 16 + l15) * 128 + bcol);
      __builtin_amdgcn_s_setprio(1);
      #pragma unroll
      for (int mi = 0; mi < 4; ++mi)
        #pragma unroll
        for (int ni = 0; ni < 4; ++ni)
          acc[mi][ni] = __builtin_amdgcn_mfma_f32_16x16x32_bf16(av[mi], bv[ni], acc[mi][ni], 0, 0, 0);
      __builtin_amdgcn_s_setprio(0);
    }
  };

  u16* pb0 = lds;
  u16* pb1 = lds + 24576;
  u16* pb2 = lds + 49152;

  stage(0, pb0);
  stage(1, pb1);
  for (int t = 0; t < nK; ++t) {
    if (t + 1 < nK) {
      asm volatile("s_waitcnt vmcnt(6)" ::: "memory");
    } else {
      asm volatile("s_waitcnt vmcnt(0)" ::: "memory");
    }
    __builtin_amdgcn_s_barrier();
    if (t + 2 < nK) stage(t + 2, pb2);
    compute(pb0);
    u16* tmp = pb0; pb0 = pb1; pb1 = pb2; pb2 = tmp;
  }

  #pragma unroll
  for (int mi = 0; mi < 4; ++mi) {
    #pragma unroll
    for (int ni = 0; ni < 4; ++ni) {
      #pragma unroll
      for (int j = 0; j < 4; ++j) {
        const int grow = row0 + wr + mi * 16 + l4 * 4 + j;
        const int gcol = col0 + wc + ni * 16 + l15;
        const float v = acc[mi][ni][j];
        if constexpr (MODE == GM_PLAIN) {
          Cb[((size_t)grow << 10) + gcol] = f2bf(v);
        } else if constexpr (MODE == GM_PROJ) {
          const size_t o = ((size_t)grow << 10) + gcol;
          Cf[o] = v + bias[gcol] + resid[o];
        }
      }
    }
  }
}

// ---------------- GEMM B: 256x128 tile, BK=32, triple-buffer 72KB -> 2 blocks/CU
// for grid-512 GEMMs: conv (split-K x2, f32 partials) and fused KV.
template<int MODE, int SPLITK>
__global__ __launch_bounds__(512, 4)
void gemm5_k(const u16* __restrict__ A, const u16* __restrict__ B,
             u16* __restrict__ Cb, u16* __restrict__ Cb2, float* __restrict__ Cf,
             const u16* __restrict__ zb, int Ktot, int ntn_sh) {
  // per buffer: A 256x32 (8192 u16) + B 128x32 (4096 u16) = 24 KB; x3 = 72 KB
  __shared__ u16 lds[3 * 12288];
  const int tid = threadIdx.x;
  const int lane = tid & 63;
  const int w = tid >> 6;
  const int l15 = lane & 15, l4 = lane >> 4;

  const int nwg = gridDim.x;
  const int bid = blockIdx.x;
  const int lb = (bid & 7) * (nwg >> 3) + (bid >> 3);
  int kz = 0, lbt = lb;
  if constexpr (SPLITK) { kz = lb >> 8; lbt = lb & 255; }
  const int tm = lbt >> ntn_sh;
  const int tn = lbt & ((1 << ntn_sh) - 1);
  const int row0 = tm * 256, col0 = tn * 128;
  const int wr = (w >> 1) * 64, wc = (w & 1) * 64;

  // staging geometry: granule g = u*512+tid (A), tid (B); row = g>>2, gc = g&3
  const int str = tid >> 2;       // 0..127
  const int sgc = tid & 3;

  int am[2], ay[2], ax[2];
  #pragma unroll
  for (int u = 0; u < 2; ++u) {
    const int m = row0 + u * 128 + str;
    am[u] = m;
    const int s = m & 1023;
    ay[u] = s >> 5; ax[u] = s & 31;
  }

  f32x4 acc[4][4];
  #pragma unroll
  for (int i = 0; i < 4; ++i)
    #pragma unroll
    for (int jj = 0; jj < 4; ++jj)
      acc[i][jj] = (f32x4){0.f, 0.f, 0.f, 0.f};

  const int nKt = Ktot >> 5;
  const int kbase = SPLITK ? kz * Ktot : 0;

  auto stage = [&](int kt, u16* buf) {
    const int gk0 = kbase + (kt << 5);
    if constexpr (MODE == GM_CONV) {
      const int q = gk0 >> 11;          // kernel-offset plane 0..8 (const in tile)
      const int ks0 = gk0 & 2047;
      const int qd = (q >= 6) ? 2 : (q >= 3) ? 1 : 0;
      const int dy = qd - 1, dx = q - qd * 3 - 1;
      const int dd = (dy << 5) + dx;
      #pragma unroll
      for (int u = 0; u < 2; ++u) {
        const int r = u * 128 + str;
        const int swz = sgc ^ ((r >> 1) & 3);
        const int yy = ay[u] + dy, xx = ax[u] + dx;
        const bool valid = ((unsigned)yy < 32u) && ((unsigned)xx < 32u);
        const u16* ga = valid ? A + (((size_t)(am[u] + dd)) << 11) + ks0 + swz * 8 : zb;
        gload16(ga, buf + ((size_t)u * 512 + tid) * 8);
      }
      {
        const int swz = sgc ^ ((str >> 1) & 3);
        const u16* gb = B + ((size_t)q << 21) + ((size_t)(col0 + str) << 11) + ks0 + swz * 8;
        gload16(gb, buf + 8192 + (size_t)tid * 8);
      }
    } else {
      const int k0 = gk0;
      #pragma unroll
      for (int u = 0; u < 2; ++u) {
        const int r = u * 128 + str;
        const int swz = sgc ^ ((r >> 1) & 3);
        const u16* ga = A + (size_t)(row0 + r) * Ktot + k0 + swz * 8;
        gload16(ga, buf + ((size_t)u * 512 + tid) * 8);
      }
      {
        const int swz = sgc ^ ((str >> 1) & 3);
        const u16* gb = B + (size_t)(col0 + str) * Ktot + k0 + swz * 8;
        gload16(gb, buf + 8192 + (size_t)tid * 8);
      }
    }
  };

  auto compute = [&](const u16* buf) {
    short8 av[4], bv[4];
    #pragma unroll
    for (int mi = 0; mi < 4; ++mi) {
      const int row = wr + mi * 16 + l15;
      const int g = l4 ^ ((row >> 1) & 3);
      av[mi] = *(const short8*)(buf + row * 32 + g * 8);
    }
    #pragma unroll
    for (int ni = 0; ni < 4; ++ni) {
      const int row = wc + ni * 16 + l15;
      const int g = l4 ^ ((row >> 1) & 3);
      bv[ni] = *(const short8*)(buf + 8192 + row * 32 + g * 8);
    }
    __builtin_amdgcn_s_setprio(1);
    #pragma unroll
    for (int mi = 0; mi < 4; ++mi)
      #pragma unroll
      for (int ni = 0; ni < 4; ++ni)
        acc[mi][ni] = __builtin_amdgcn_mfma_f32_16x16x32_bf16(av[mi], bv[ni], acc[mi][ni], 0, 0, 0);
    __builtin_amdgcn_s_setprio(0);
  };

  u16* pb0 = lds;
  u16* pb1 = lds + 12288;
  u16* pb2 = lds + 24576;

  stage(0, pb0);
  stage(1, pb1);
  for (int t = 0; t < nKt; ++t) {
    if (t + 1 < nKt) {
      asm volatile("s_waitcnt vmcnt(3)" ::: "memory");
    } else {
      asm volatile("s_waitcnt vmcnt(0)" ::: "memory");
    }
    __builtin_amdgcn_s_barrier();
    if (t + 2 < nKt) stage(t + 2, pb2);
    compute(pb0);
    u16* tmp = pb0; pb0 = pb1; pb1 = pb2; pb2 = tmp;
  }

  #pragma unroll
  for (int mi = 0; mi < 4; ++mi) {
    #pragma unroll
    for (int ni = 0; ni < 4; ++ni) {
      #pragma unroll
      for (int j = 0; j < 4; ++j) {
        const int grow = row0 + wr + mi * 16 + l4 * 4 + j;
        const int gcol = col0 + wc + ni * 16 + l15;
        const float v = acc[mi][ni][j];
        if constexpr (MODE == GM_CONV) {
          // f32 partial, layout [kz][m][o]
          Cf[(size_t)kz * 8388608 + ((size_t)grow << 10) + gcol] = v;
        } else if constexpr (MODE == GM_KV) {
          if (gcol < 1024) {
            Cb[((size_t)grow << 10) + gcol] = f2bf(v);
          } else {
            const int c = gcol - 1024;
            const int b = grow >> 10, ms = grow & 1023;
            const int h = c >> 7, d = c & 127;
            Cb2[((size_t)((b * 8 + h) * 128 + d) << 10) + ms] = f2bf(v);
          }
        }
      }
    }
  }
}

// ---------------- flash attention (double-buffered, 1 barrier/iter) ----------------
__global__ __launch_bounds__(256, 2)
void attn2_k(const u16* __restrict__ Q, const u16* __restrict__ K,
             const u16* __restrict__ Vt, u16* __restrict__ O) {
  __shared__ u16 Ks[2][64 * 128];
  __shared__ u16 Vs[2][128 * 64];
  __shared__ u16 Plds[4][16 * 80];
  const int mtile = blockIdx.x;
  const int bh = blockIdx.y;
  const int b = bh >> 3, h = bh & 7;
  const int tid = threadIdx.x, lane = tid & 63, w = tid >> 6;
  const int l15 = lane & 15, l4 = lane >> 4;

  short8 qf[4];
  {
    const int qrow = b * 1024 + mtile * 64 + w * 16 + l15;
    const u16* qb = Q + ((size_t)qrow << 10) + h * 128;
    #pragma unroll
    for (int kk = 0; kk < 4; ++kk)
      qf[kk] = *(const short8*)(qb + kk * 32 + l4 * 8);
  }

  f32x4 o[8];
  #pragma unroll
  for (int db = 0; db < 8; ++db) o[db] = (f32x4){0.f, 0.f, 0.f, 0.f};
  float mrow[4], lrow[4];
  #pragma unroll
  for (int j = 0; j < 4; ++j) { mrow[j] = -1e30f; lrow[j] = 0.f; }
  const float scale = 0.08838834764831845f;  // 128^-0.5

  auto stageKV = [&](int kt, int half) {
    #pragma unroll
    for (int j = 0; j < 4; ++j) {
      const int c = (j * 4 + w) * 64 + lane;
      const int r = c >> 4;
      const int coff = (((c & 15) ^ (r & 7)) << 3);
      const u16* gp = K + ((size_t)(b * 1024 + kt * 64 + r) << 10) + h * 128 + coff;
      gload16(gp, (void*)(Ks[half] + (j * 4 + w) * 512));
    }
    #pragma unroll
    for (int j = 0; j < 4; ++j) {
      const int c = (j * 4 + w) * 64 + lane;
      const int r = c >> 3;
      const int coff = (((c & 7) ^ (r & 7)) << 3);
      const u16* gp = Vt + ((size_t)((b * 8 + h) * 128 + r) << 10) + kt * 64 + coff;
      gload16(gp, (void*)(Vs[half] + (j * 4 + w) * 512));
    }
  };

  stageKV(0, 0);
  for (int kt = 0; kt < 16; ++kt) {
    const int cur = kt & 1;
    asm volatile("s_waitcnt vmcnt(0)" ::: "memory");
    __builtin_amdgcn_s_barrier();
    if (kt + 1 < 16) stageKV(kt + 1, cur ^ 1);

    const u16* ks_ = Ks[cur];
    const u16* vs_ = Vs[cur];
    f32x4 s[4];
    #pragma unroll
    for (int cb = 0; cb < 4; ++cb) {
      s[cb] = (f32x4){0.f, 0.f, 0.f, 0.f};
      #pragma unroll
      for (int kk = 0; kk < 4; ++kk) {
        const int col = (kk * 32 + l4 * 8) ^ ((l15 & 7) << 3);
        short8 bK = *(const short8*)(ks_ + (cb * 16 + l15) * 128 + col);
        s[cb] = __builtin_amdgcn_mfma_f32_16x16x32_bf16(qf[kk], bK, s[cb], 0, 0, 0);
      }
    }
    #pragma unroll
    for (int cb = 0; cb < 4; ++cb) {
      s[cb][0] *= scale; s[cb][1] *= scale; s[cb][2] *= scale; s[cb][3] *= scale;
    }
    #pragma unroll
    for (int j = 0; j < 4; ++j) {
      float mx = fmaxf(fmaxf(s[0][j], s[1][j]), fmaxf(s[2][j], s[3][j]));
      #pragma unroll
      for (int off = 8; off >= 1; off >>= 1)
        mx = fmaxf(mx, __shfl_xor(mx, off, 64));
      const float mn = fmaxf(mrow[j], mx);
      const float fac = __expf(mrow[j] - mn);
      mrow[j] = mn;
      float rs = 0.f;
      #pragma unroll
      for (int cb = 0; cb < 4; ++cb) {
        const float p = __expf(s[cb][j] - mn);
        s[cb][j] = p;
        rs += p;
      }
      #pragma unroll
      for (int off = 8; off >= 1; off >>= 1)
        rs += __shfl_xor(rs, off, 64);
      lrow[j] = lrow[j] * fac + rs;
      #pragma unroll
      for (int db = 0; db < 8; ++db) o[db][j] *= fac;
    }
    u16* pl = Plds[w];
    #pragma unroll
    for (int cb = 0; cb < 4; ++cb)
      #pragma unroll
      for (int j = 0; j < 4; ++j)
        pl[(l4 * 4 + j) * 80 + cb * 16 + l15] = f2bf(s[cb][j]);
    asm volatile("s_waitcnt lgkmcnt(0)" ::: "memory");
    __builtin_amdgcn_sched_barrier(0);
    short8 ap[2];
    #pragma unroll
    for (int ks2 = 0; ks2 < 2; ++ks2)
      ap[ks2] = *(const short8*)(pl + l15 * 80 + ks2 * 32 + l4 * 8);
    #pragma unroll
    for (int db = 0; db < 8; ++db) {
      #pragma unroll
      for (int ks2 = 0; ks2 < 2; ++ks2) {
        const int col = (ks2 * 32 + l4 * 8) ^ ((l15 & 7) << 3);
        short8 bV = *(const short8*)(vs_ + (db * 16 + l15) * 64 + col);
        o[db] = __builtin_amdgcn_mfma_f32_16x16x32_bf16(ap[ks2], bV, o[db], 0, 0, 0);
      }
    }
  }
  #pragma unroll
  for (int db = 0; db < 8; ++db) {
    #pragma unroll
    for (int j = 0; j < 4; ++j) {
      const int grow = b * 1024 + mtile * 64 + w * 16 + l4 * 4 + j;
      const int gcol = h * 128 + db * 16 + l15;
      O[((size_t)grow << 10) + gcol] = f2bf(o[db][j] / lrow[j]);
    }
  }
}

// ---------------- launch ----------------

extern "C" void kernel_launch(void* const* d_in, const int* in_sizes, int n_in,
                              void* d_out, int out_size, void* d_ws, size_t ws_size,
                              hipStream_t stream) {
  const float* x1     = (const float*)d_in[0];
  const float* x2     = (const float*)d_in[1];
  const float* conv_w = (const float*)d_in[2];
  const float* conv_b = (const float*)d_in[3];
  const float* wq     = (const float*)d_in[4];
  const float* wk     = (const float*)d_in[5];
  const float* wv     = (const float*)d_in[6];
  const float* proj_w = (const float*)d_in[7];
  const float* proj_b = (const float*)d_in[8];
  float* out = (float*)d_out;

  char* ws = (char*)d_ws;
  size_t off = 0;
  auto alloc = [&](size_t bytes) -> void* {
    void* p = ws + off;
    off += (bytes + 255) & ~(size_t)255;
    return p;
  };
  u16* x1b  = (u16*)alloc(8192ULL * 1024 * 2);
  u16* in_t = (u16*)alloc(8ULL * 1024 * 2048 * 2);
  u16* Wp   = (u16*)alloc(9ULL * 2097152 * 2);
  u16* wqb  = (u16*)alloc(1048576ULL * 2);
  u16* wkb  = (u16*)alloc(1048576ULL * 2);  // contiguous with wvb -> fused KV B
  u16* wvb  = (u16*)alloc(1048576ULL * 2);
  u16* pjb  = (u16*)alloc(1048576ULL * 2);
  u16* xc   = (u16*)alloc(8192ULL * 1024 * 2);
  u16* Qb   = (u16*)alloc(8192ULL * 1024 * 2);
  u16* Kb   = (u16*)alloc(8192ULL * 1024 * 2);
  u16* Vtb  = (u16*)alloc(8192ULL * 1024 * 2);
  u16* Ob   = (u16*)alloc(8192ULL * 1024 * 2);
  u16* zb   = (u16*)alloc(256);
  // split-K f32 partials (2 x 8192 x 1024 f32 = 64 MB) alias Qb..Ob (dead until Q GEMM)
  float* pConv = (float*)Qb;

  // prep
  cast4_k<<<dim3(1024, 4), 256, 0, stream>>>(wq, wk, wv, proj_w, wqb, wkb, wvb, pjb);
  build_int2<<<dim3(32, 16, 8), 256, 0, stream>>>(x1, x2, in_t, x1b);
  pack_wp<<<8192, 256, 0, stream>>>(conv_w, Wp);
  zero_k<<<1, 128, 0, stream>>>(zb);

  // conv as implicit GEMM, split-K x2 (each half K=9216), f32 partials
  gemm5_k<GM_CONV, 1><<<512, 512, 0, stream>>>(in_t, Wp, nullptr, nullptr, pConv, zb, 9216, 3);
  // combine partials + bias, transpose to xc[b][o][s]
  addc_k<<<dim3(16, 16, 8), 256, 0, stream>>>(pConv, conv_b, xc);
  // Q
  gemm3_k<GM_PLAIN><<<256, 512, 0, stream>>>(x1b, wqb, Qb, nullptr, nullptr, nullptr, 1024, 3);
  // fused K+V (B = [wk;wv] contiguous, N=2048), 512 blocks at 2/CU
  gemm5_k<GM_KV, 0><<<512, 512, 0, stream>>>(xc, wkb, Kb, Vtb, nullptr, zb, 1024, 4);
  // attention
  attn2_k<<<dim3(16, 64), 256, 0, stream>>>(Qb, Kb, Vtb, Ob);
  // projection + bias + residual (f32 out)
  gemm3_k<GM_PROJ><<<256, 512, 0, stream>>>(Ob, pjb, nullptr, out, proj_b, x1, 1024, 3);
}

// Round 6
// 573.698 us; speedup vs baseline: 1.0533x; 1.0252x over previous
//
#include <hip/hip_runtime.h>
#include <hip/hip_bf16.h>
#include <cstdint>
#include <cstddef>

typedef __attribute__((ext_vector_type(8))) short short8;
typedef __attribute__((ext_vector_type(4))) float f32x4;
typedef unsigned short u16;

static __device__ __forceinline__ u16 f2bf(float f) {
  __hip_bfloat16 h = __float2bfloat16(f);
  return *reinterpret_cast<u16*>(&h);
}

static __device__ __forceinline__ void gload16(const void* g, void* l) {
  __builtin_amdgcn_global_load_lds(
      (const __attribute__((address_space(1))) void*)g,
      (__attribute__((address_space(3))) void*)l, 16, 0, 0);
}

// ---------------- prep kernels ----------------

// all four weight casts in one dispatch
__global__ void cast4_k(const float* __restrict__ a, const float* __restrict__ b,
                        const float* __restrict__ c, const float* __restrict__ d,
                        u16* __restrict__ oa, u16* __restrict__ ob,
                        u16* __restrict__ oc, u16* __restrict__ od) {
  const int which = blockIdx.y;
  const float* src = (which == 0) ? a : (which == 1) ? b : (which == 2) ? c : d;
  u16* dst = (which == 0) ? oa : (which == 1) ? ob : (which == 2) ? oc : od;
  int i = blockIdx.x * 256 + threadIdx.x;   // 262144 float4 per tensor
  float4 v = ((const float4*)src)[i];
  union { u16 u[4]; uint2 p; } r;
  r.u[0] = f2bf(v.x); r.u[1] = f2bf(v.y); r.u[2] = f2bf(v.z); r.u[3] = f2bf(v.w);
  ((uint2*)dst)[i] = r.p;
}

// in_t[b][s][i] = bf16( concat(x1,x2)[b][i][s] );  also emits x1b = bf16(x1) flat
__global__ void build_int2(const float* __restrict__ x1, const float* __restrict__ x2,
                           u16* __restrict__ in_t, u16* __restrict__ x1b) {
  __shared__ float tile[64][65];
  const int it = blockIdx.x;   // 32 i-tiles
  const int st = blockIdx.y;   // 16 s-tiles
  const int b  = blockIdx.z;   // 8
  const int i0 = it * 64, s0 = st * 64;
  const bool isx1 = (i0 < 1024);
  const float* src = isx1
      ? x1 + ((size_t)b * 1024 + i0) * 1024
      : x2 + ((size_t)b * 1024 + (i0 - 1024)) * 1024;
  const int t = threadIdx.x;
  #pragma unroll
  for (int jj = 0; jj < 16; ++jj) {
    int idx = jj * 256 + t;
    int ii = idx >> 6, si = idx & 63;
    float v = src[(size_t)ii * 1024 + s0 + si];
    tile[ii][si] = v;
    if (isx1)
      x1b[((size_t)b * 1024 + i0 + ii) * 1024 + s0 + si] = f2bf(v);
  }
  __syncthreads();
  #pragma unroll
  for (int jj = 0; jj < 16; ++jj) {
    int idx = jj * 256 + t;
    int si = idx >> 6, ii = idx & 63;
    in_t[((size_t)b * 1024 + s0 + si) * 2048 + i0 + ii] = f2bf(tile[ii][si]);
  }
}

// Wp[q][o][i] = bf16( conv_w[o][i][q] ),  q = ky*3+kx
__global__ void pack_wp(const float* __restrict__ cw, u16* __restrict__ Wp) {
  __shared__ float sb[2304];
  const int blk = blockIdx.x;  // 8192
  const int t = threadIdx.x;   // 256
  const size_t base = (size_t)blk * 2304;
  #pragma unroll
  for (int jj = 0; jj < 9; ++jj) sb[jj * 256 + t] = cw[base + jj * 256 + t];
  __syncthreads();
  const int p = blk * 256 + t;  // (o,i) linear
  #pragma unroll
  for (int q = 0; q < 9; ++q)
    Wp[(size_t)q * 2097152 + p] = f2bf(sb[t * 9 + q]);
}

__global__ void zero_k(u16* z) { z[threadIdx.x] = 0; }

// split-K combine: xc[b][o][s] = bf16(p0 + p1 + bias[o]); p is [kz][b*1024+s][o] f32
__global__ void addc_k(const float* __restrict__ p, const float* __restrict__ bias,
                       u16* __restrict__ xc) {
  __shared__ float tile[64][65];
  const int st = blockIdx.x;   // 16 s-tiles
  const int ot = blockIdx.y;   // 16 o-tiles
  const int b  = blockIdx.z;   // 8
  const int s0 = st * 64, o0 = ot * 64;
  const int t = threadIdx.x;
  const float* p1 = p + 8388608;
  #pragma unroll
  for (int jj = 0; jj < 16; ++jj) {
    int idx = jj * 256 + t;
    int si = idx >> 6, oi = idx & 63;
    const size_t m = ((size_t)b * 1024 + s0 + si) * 1024 + o0 + oi;
    tile[si][oi] = p[m] + p1[m] + bias[o0 + oi];
  }
  __syncthreads();
  #pragma unroll
  for (int jj = 0; jj < 16; ++jj) {
    int idx = jj * 256 + t;
    int oi = idx >> 6, si = idx & 63;
    xc[((size_t)b * 1024 + o0 + oi) * 1024 + s0 + si] = f2bf(tile[si][oi]);
  }
}

enum { GM_PLAIN = 0, GM_VT = 1, GM_PROJ = 2, GM_CONV = 3, GM_KV = 4 };

// ---------------- GEMM A: 256x128 tile, BK=64, triple-buffer 144KB (round-3 915TF)
// for grid-256 GEMMs (Q, proj) where 2 blocks/CU is unreachable anyway.
template<int MODE>
__global__ __launch_bounds__(512, 2)
void gemm3_k(const u16* __restrict__ A, const u16* __restrict__ B,
             u16* __restrict__ Cb, float* __restrict__ Cf,
             const float* __restrict__ bias, const float* __restrict__ resid,
             int Ktot, int ntn_sh) {
  __shared__ u16 lds[3 * 24576];
  const int tid = threadIdx.x;
  const int lane = tid & 63;
  const int w = tid >> 6;
  const int l15 = lane & 15, l4 = lane >> 4;

  const int nwg = gridDim.x;
  const int bid = blockIdx.x;
  const int lb = (bid & 7) * (nwg >> 3) + (bid >> 3);
  const int tm = lb >> ntn_sh;
  const int tn = lb & ((1 << ntn_sh) - 1);
  const int row0 = tm * 256, col0 = tn * 128;
  const int wr = (w >> 1) * 64, wc = (w & 1) * 64;

  const int sr = w * 8 + (lane >> 3);
  const int pp = (lane & 7) ^ (lane >> 3);

  f32x4 acc[4][4];
  #pragma unroll
  for (int i = 0; i < 4; ++i)
    #pragma unroll
    for (int jj = 0; jj < 4; ++jj)
      acc[i][jj] = (f32x4){0.f, 0.f, 0.f, 0.f};

  const int nK = Ktot >> 6;

  auto stage = [&](int kt, u16* buf) {
    u16* da = buf + (size_t)w * 512;
    u16* db = buf + 16384 + (size_t)w * 512;
    const int k0 = kt << 6;
    #pragma unroll
    for (int u = 0; u < 4; ++u) {
      const u16* ga = A + (size_t)(row0 + u * 64 + sr) * Ktot + k0 + pp * 8;
      gload16(ga, da + u * 4096);
    }
    #pragma unroll
    for (int u = 0; u < 2; ++u) {
      const u16* gb = B + (size_t)(col0 + u * 64 + sr) * Ktot + k0 + pp * 8;
      gload16(gb, db + u * 4096);
    }
  };

  auto compute = [&](const u16* buf) {
    const char* Ar = (const char*)buf;
    const char* Br = (const char*)(buf + 16384);
    #pragma unroll
    for (int ks = 0; ks < 2; ++ks) {
      const int bcol = ((ks << 6) + (l4 << 4)) ^ ((l15 & 7) << 4);
      short8 av[4], bv[4];
      #pragma unroll
      for (int mi = 0; mi < 4; ++mi)
        av[mi] = *(const short8*)(Ar + (wr + mi * 16 + l15) * 128 + bcol);
      #pragma unroll
      for (int ni = 0; ni < 4; ++ni)
        bv[ni] = *(const short8*)(Br + (wc + ni * 16 + l15) * 128 + bcol);
      __builtin_amdgcn_s_setprio(1);
      #pragma unroll
      for (int mi = 0; mi < 4; ++mi)
        #pragma unroll
        for (int ni = 0; ni < 4; ++ni)
          acc[mi][ni] = __builtin_amdgcn_mfma_f32_16x16x32_bf16(av[mi], bv[ni], acc[mi][ni], 0, 0, 0);
      __builtin_amdgcn_s_setprio(0);
    }
  };

  u16* pb0 = lds;
  u16* pb1 = lds + 24576;
  u16* pb2 = lds + 49152;

  stage(0, pb0);
  stage(1, pb1);
  for (int t = 0; t < nK; ++t) {
    if (t + 1 < nK) {
      asm volatile("s_waitcnt vmcnt(6)" ::: "memory");
    } else {
      asm volatile("s_waitcnt vmcnt(0)" ::: "memory");
    }
    __builtin_amdgcn_s_barrier();
    if (t + 2 < nK) stage(t + 2, pb2);
    compute(pb0);
    u16* tmp = pb0; pb0 = pb1; pb1 = pb2; pb2 = tmp;
  }

  #pragma unroll
  for (int mi = 0; mi < 4; ++mi) {
    #pragma unroll
    for (int ni = 0; ni < 4; ++ni) {
      #pragma unroll
      for (int j = 0; j < 4; ++j) {
        const int grow = row0 + wr + mi * 16 + l4 * 4 + j;
        const int gcol = col0 + wc + ni * 16 + l15;
        const float v = acc[mi][ni][j];
        if constexpr (MODE == GM_PLAIN) {
          Cb[((size_t)grow << 10) + gcol] = f2bf(v);
        } else if constexpr (MODE == GM_PROJ) {
          const size_t o = ((size_t)grow << 10) + gcol;
          Cf[o] = v + bias[gcol] + resid[o];
        }
      }
    }
  }
}

// ---------------- GEMM B: 256x128 tile, BK=32, 8 waves, 72KB -> 2 blocks/CU
// kept for the fused-KV GEMM (512 natural blocks).
template<int MODE>
__global__ __launch_bounds__(512, 4)
void gemm5_k(const u16* __restrict__ A, const u16* __restrict__ B,
             u16* __restrict__ Cb, u16* __restrict__ Cb2,
             const u16* __restrict__ zb, int Ktot, int ntn_sh) {
  __shared__ u16 lds[3 * 12288];
  const int tid = threadIdx.x;
  const int lane = tid & 63;
  const int w = tid >> 6;
  const int l15 = lane & 15, l4 = lane >> 4;

  const int nwg = gridDim.x;
  const int bid = blockIdx.x;
  const int lb = (bid & 7) * (nwg >> 3) + (bid >> 3);
  const int tm = lb >> ntn_sh;
  const int tn = lb & ((1 << ntn_sh) - 1);
  const int row0 = tm * 256, col0 = tn * 128;
  const int wr = (w >> 1) * 64, wc = (w & 1) * 64;

  const int str = tid >> 2;       // 0..127
  const int sgc = tid & 3;

  f32x4 acc[4][4];
  #pragma unroll
  for (int i = 0; i < 4; ++i)
    #pragma unroll
    for (int jj = 0; jj < 4; ++jj)
      acc[i][jj] = (f32x4){0.f, 0.f, 0.f, 0.f};

  const int nKt = Ktot >> 5;

  auto stage = [&](int kt, u16* buf) {
    const int k0 = kt << 5;
    #pragma unroll
    for (int u = 0; u < 2; ++u) {
      const int r = u * 128 + str;
      const int swz = sgc ^ ((r >> 1) & 3);
      const u16* ga = A + (size_t)(row0 + r) * Ktot + k0 + swz * 8;
      gload16(ga, buf + ((size_t)u * 512 + tid) * 8);
    }
    {
      const int swz = sgc ^ ((str >> 1) & 3);
      const u16* gb = B + (size_t)(col0 + str) * Ktot + k0 + swz * 8;
      gload16(gb, buf + 8192 + (size_t)tid * 8);
    }
  };

  auto compute = [&](const u16* buf) {
    short8 av[4], bv[4];
    #pragma unroll
    for (int mi = 0; mi < 4; ++mi) {
      const int row = wr + mi * 16 + l15;
      const int g = l4 ^ ((row >> 1) & 3);
      av[mi] = *(const short8*)(buf + row * 32 + g * 8);
    }
    #pragma unroll
    for (int ni = 0; ni < 4; ++ni) {
      const int row = wc + ni * 16 + l15;
      const int g = l4 ^ ((row >> 1) & 3);
      bv[ni] = *(const short8*)(buf + 8192 + row * 32 + g * 8);
    }
    __builtin_amdgcn_s_setprio(1);
    #pragma unroll
    for (int mi = 0; mi < 4; ++mi)
      #pragma unroll
      for (int ni = 0; ni < 4; ++ni)
        acc[mi][ni] = __builtin_amdgcn_mfma_f32_16x16x32_bf16(av[mi], bv[ni], acc[mi][ni], 0, 0, 0);
    __builtin_amdgcn_s_setprio(0);
  };

  u16* pb0 = lds;
  u16* pb1 = lds + 12288;
  u16* pb2 = lds + 24576;

  stage(0, pb0);
  stage(1, pb1);
  for (int t = 0; t < nKt; ++t) {
    if (t + 1 < nKt) {
      asm volatile("s_waitcnt vmcnt(3)" ::: "memory");
    } else {
      asm volatile("s_waitcnt vmcnt(0)" ::: "memory");
    }
    __builtin_amdgcn_s_barrier();
    if (t + 2 < nKt) stage(t + 2, pb2);
    compute(pb0);
    u16* tmp = pb0; pb0 = pb1; pb1 = pb2; pb2 = tmp;
  }

  #pragma unroll
  for (int mi = 0; mi < 4; ++mi) {
    #pragma unroll
    for (int ni = 0; ni < 4; ++ni) {
      #pragma unroll
      for (int j = 0; j < 4; ++j) {
        const int grow = row0 + wr + mi * 16 + l4 * 4 + j;
        const int gcol = col0 + wc + ni * 16 + l15;
        const float v = acc[mi][ni][j];
        if constexpr (MODE == GM_KV) {
          if (gcol < 1024) {
            Cb[((size_t)grow << 10) + gcol] = f2bf(v);
          } else {
            const int c = gcol - 1024;
            const int b = grow >> 10, ms = grow & 1023;
            const int h = c >> 7, d = c & 127;
            Cb2[((size_t)((b * 8 + h) * 128 + d) << 10) + ms] = f2bf(v);
          }
        }
      }
    }
  }
}

// ---------------- GEMM C (conv): 256x128 tile, BK=32, 4 waves, wave tile 64x128
// 72KB triple-buffer -> 2 blocks/CU; 25% fewer LDS-read bytes per MFMA than the
// 8-wave 64x64 layout (LDS-read-BW was the measured 48% ceiling).
template<int SPLITK>
__global__ __launch_bounds__(256, 2)
void gemm6_k(const u16* __restrict__ A, const u16* __restrict__ B,
             float* __restrict__ Cf, const u16* __restrict__ zb,
             int Ktot, int ntn_sh) {
  __shared__ u16 lds[3 * 12288];
  const int tid = threadIdx.x;       // 256
  const int lane = tid & 63;
  const int w = tid >> 6;            // 0..3
  const int l15 = lane & 15, l4 = lane >> 4;

  const int nwg = gridDim.x;
  const int bid = blockIdx.x;
  const int lb = (bid & 7) * (nwg >> 3) + (bid >> 3);
  int kz = 0, lbt = lb;
  if constexpr (SPLITK) { kz = lb >> 8; lbt = lb & 255; }
  const int tm = lbt >> ntn_sh;
  const int tn = lbt & ((1 << ntn_sh) - 1);
  const int row0 = tm * 256, col0 = tn * 128;
  const int wr = w * 64;

  // staging: 256 threads; row = u*64 + (tid>>2), granule col = tid&3
  const int str = tid >> 2;          // 0..63
  const int sgc = tid & 3;
  const int swz = sgc ^ ((str >> 1) & 3);   // same for all u (u*64 keeps bits 1..2 of row)

  int am[4], ay[4], ax[4];
  #pragma unroll
  for (int u = 0; u < 4; ++u) {
    const int m = row0 + u * 64 + str;
    am[u] = m;
    const int s = m & 1023;
    ay[u] = s >> 5; ax[u] = s & 31;
  }

  f32x4 acc[4][8];
  #pragma unroll
  for (int i = 0; i < 4; ++i)
    #pragma unroll
    for (int jj = 0; jj < 8; ++jj)
      acc[i][jj] = (f32x4){0.f, 0.f, 0.f, 0.f};

  const int nKt = Ktot >> 5;
  const int kbase = SPLITK ? kz * Ktot : 0;

  auto stage = [&](int kt, u16* buf) {
    const int gk0 = kbase + (kt << 5);
    const int q = gk0 >> 11;           // kernel-offset plane 0..8 (const in tile)
    const int ks0 = gk0 & 2047;
    const int qd = (q >= 6) ? 2 : (q >= 3) ? 1 : 0;
    const int dy = qd - 1, dx = q - qd * 3 - 1;
    const int dd = (dy << 5) + dx;
    #pragma unroll
    for (int u = 0; u < 4; ++u) {
      const int yy = ay[u] + dy, xx = ax[u] + dx;
      const bool valid = ((unsigned)yy < 32u) && ((unsigned)xx < 32u);
      const u16* ga = valid ? A + (((size_t)(am[u] + dd)) << 11) + ks0 + swz * 8 : zb;
      gload16(ga, buf + ((size_t)u * 256 + tid) * 8);
    }
    #pragma unroll
    for (int u = 0; u < 2; ++u) {
      const u16* gb = B + ((size_t)q << 21) + ((size_t)(col0 + u * 64 + str) << 11) + ks0 + swz * 8;
      gload16(gb, buf + 8192 + ((size_t)u * 256 + tid) * 8);
    }
  };

  auto compute = [&](const u16* buf) {
    short8 av[4], bv[8];
    #pragma unroll
    for (int mi = 0; mi < 4; ++mi) {
      const int row = wr + mi * 16 + l15;
      const int g = l4 ^ ((row >> 1) & 3);
      av[mi] = *(const short8*)(buf + row * 32 + g * 8);
    }
    #pragma unroll
    for (int ni = 0; ni < 8; ++ni) {
      const int row = ni * 16 + l15;
      const int g = l4 ^ ((row >> 1) & 3);
      bv[ni] = *(const short8*)(buf + 8192 + row * 32 + g * 8);
    }
    __builtin_amdgcn_s_setprio(1);
    #pragma unroll
    for (int mi = 0; mi < 4; ++mi)
      #pragma unroll
      for (int ni = 0; ni < 8; ++ni)
        acc[mi][ni] = __builtin_amdgcn_mfma_f32_16x16x32_bf16(av[mi], bv[ni], acc[mi][ni], 0, 0, 0);
    __builtin_amdgcn_s_setprio(0);
  };

  u16* pb0 = lds;
  u16* pb1 = lds + 12288;
  u16* pb2 = lds + 24576;

  stage(0, pb0);
  stage(1, pb1);
  for (int t = 0; t < nKt; ++t) {
    if (t + 1 < nKt) {
      asm volatile("s_waitcnt vmcnt(6)" ::: "memory");
    } else {
      asm volatile("s_waitcnt vmcnt(0)" ::: "memory");
    }
    __builtin_amdgcn_s_barrier();
    if (t + 2 < nKt) stage(t + 2, pb2);
    compute(pb0);
    u16* tmp = pb0; pb0 = pb1; pb1 = pb2; pb2 = tmp;
  }

  // epilogue: f32 partials, layout [kz][m][o]
  #pragma unroll
  for (int mi = 0; mi < 4; ++mi) {
    #pragma unroll
    for (int ni = 0; ni < 8; ++ni) {
      #pragma unroll
      for (int j = 0; j < 4; ++j) {
        const int grow = row0 + wr + mi * 16 + l4 * 4 + j;
        const int gcol = col0 + ni * 16 + l15;
        Cf[(size_t)kz * 8388608 + ((size_t)grow << 10) + gcol] = acc[mi][ni][j];
      }
    }
  }
}

// ---------------- flash attention (double-buffered, 1 barrier/iter) ----------------
__global__ __launch_bounds__(256, 2)
void attn2_k(const u16* __restrict__ Q, const u16* __restrict__ K,
             const u16* __restrict__ Vt, u16* __restrict__ O) {
  __shared__ u16 Ks[2][64 * 128];
  __shared__ u16 Vs[2][128 * 64];
  __shared__ u16 Plds[4][16 * 80];
  const int mtile = blockIdx.x;
  const int bh = blockIdx.y;
  const int b = bh >> 3, h = bh & 7;
  const int tid = threadIdx.x, lane = tid & 63, w = tid >> 6;
  const int l15 = lane & 15, l4 = lane >> 4;

  short8 qf[4];
  {
    const int qrow = b * 1024 + mtile * 64 + w * 16 + l15;
    const u16* qb = Q + ((size_t)qrow << 10) + h * 128;
    #pragma unroll
    for (int kk = 0; kk < 4; ++kk)
      qf[kk] = *(const short8*)(qb + kk * 32 + l4 * 8);
  }

  f32x4 o[8];
  #pragma unroll
  for (int db = 0; db < 8; ++db) o[db] = (f32x4){0.f, 0.f, 0.f, 0.f};
  float mrow[4], lrow[4];
  #pragma unroll
  for (int j = 0; j < 4; ++j) { mrow[j] = -1e30f; lrow[j] = 0.f; }
  const float scale = 0.08838834764831845f;  // 128^-0.5

  auto stageKV = [&](int kt, int half) {
    #pragma unroll
    for (int j = 0; j < 4; ++j) {
      const int c = (j * 4 + w) * 64 + lane;
      const int r = c >> 4;
      const int coff = (((c & 15) ^ (r & 7)) << 3);
      const u16* gp = K + ((size_t)(b * 1024 + kt * 64 + r) << 10) + h * 128 + coff;
      gload16(gp, (void*)(Ks[half] + (j * 4 + w) * 512));
    }
    #pragma unroll
    for (int j = 0; j < 4; ++j) {
      const int c = (j * 4 + w) * 64 + lane;
      const int r = c >> 3;
      const int coff = (((c & 7) ^ (r & 7)) << 3);
      const u16* gp = Vt + ((size_t)((b * 8 + h) * 128 + r) << 10) + kt * 64 + coff;
      gload16(gp, (void*)(Vs[half] + (j * 4 + w) * 512));
    }
  };

  stageKV(0, 0);
  for (int kt = 0; kt < 16; ++kt) {
    const int cur = kt & 1;
    asm volatile("s_waitcnt vmcnt(0)" ::: "memory");
    __builtin_amdgcn_s_barrier();
    if (kt + 1 < 16) stageKV(kt + 1, cur ^ 1);

    const u16* ks_ = Ks[cur];
    const u16* vs_ = Vs[cur];
    f32x4 s[4];
    #pragma unroll
    for (int cb = 0; cb < 4; ++cb) {
      s[cb] = (f32x4){0.f, 0.f, 0.f, 0.f};
      #pragma unroll
      for (int kk = 0; kk < 4; ++kk) {
        const int col = (kk * 32 + l4 * 8) ^ ((l15 & 7) << 3);
        short8 bK = *(const short8*)(ks_ + (cb * 16 + l15) * 128 + col);
        s[cb] = __builtin_amdgcn_mfma_f32_16x16x32_bf16(qf[kk], bK, s[cb], 0, 0, 0);
      }
    }
    #pragma unroll
    for (int cb = 0; cb < 4; ++cb) {
      s[cb][0] *= scale; s[cb][1] *= scale; s[cb][2] *= scale; s[cb][3] *= scale;
    }
    #pragma unroll
    for (int j = 0; j < 4; ++j) {
      float mx = fmaxf(fmaxf(s[0][j], s[1][j]), fmaxf(s[2][j], s[3][j]));
      #pragma unroll
      for (int off = 8; off >= 1; off >>= 1)
        mx = fmaxf(mx, __shfl_xor(mx, off, 64));
      const float mn = fmaxf(mrow[j], mx);
      const float fac = __expf(mrow[j] - mn);
      mrow[j] = mn;
      float rs = 0.f;
      #pragma unroll
      for (int cb = 0; cb < 4; ++cb) {
        const float p = __expf(s[cb][j] - mn);
        s[cb][j] = p;
        rs += p;
      }
      #pragma unroll
      for (int off = 8; off >= 1; off >>= 1)
        rs += __shfl_xor(rs, off, 64);
      lrow[j] = lrow[j] * fac + rs;
      #pragma unroll
      for (int db = 0; db < 8; ++db) o[db][j] *= fac;
    }
    u16* pl = Plds[w];
    #pragma unroll
    for (int cb = 0; cb < 4; ++cb)
      #pragma unroll
      for (int j = 0; j < 4; ++j)
        pl[(l4 * 4 + j) * 80 + cb * 16 + l15] = f2bf(s[cb][j]);
    asm volatile("s_waitcnt lgkmcnt(0)" ::: "memory");
    __builtin_amdgcn_sched_barrier(0);
    short8 ap[2];
    #pragma unroll
    for (int ks2 = 0; ks2 < 2; ++ks2)
      ap[ks2] = *(const short8*)(pl + l15 * 80 + ks2 * 32 + l4 * 8);
    #pragma unroll
    for (int db = 0; db < 8; ++db) {
      #pragma unroll
      for (int ks2 = 0; ks2 < 2; ++ks2) {
        const int col = (ks2 * 32 + l4 * 8) ^ ((l15 & 7) << 3);
        short8 bV = *(const short8*)(vs_ + (db * 16 + l15) * 64 + col);
        o[db] = __builtin_amdgcn_mfma_f32_16x16x32_bf16(ap[ks2], bV, o[db], 0, 0, 0);
      }
    }
  }
  #pragma unroll
  for (int db = 0; db < 8; ++db) {
    #pragma unroll
    for (int j = 0; j < 4; ++j) {
      const int grow = b * 1024 + mtile * 64 + w * 16 + l4 * 4 + j;
      const int gcol = h * 128 + db * 16 + l15;
      O[((size_t)grow << 10) + gcol] = f2bf(o[db][j] / lrow[j]);
    }
  }
}

// ---------------- launch ----------------

extern "C" void kernel_launch(void* const* d_in, const int* in_sizes, int n_in,
                              void* d_out, int out_size, void* d_ws, size_t ws_size,
                              hipStream_t stream) {
  const float* x1     = (const float*)d_in[0];
  const float* x2     = (const float*)d_in[1];
  const float* conv_w = (const float*)d_in[2];
  const float* conv_b = (const float*)d_in[3];
  const float* wq     = (const float*)d_in[4];
  const float* wk     = (const float*)d_in[5];
  const float* wv     = (const float*)d_in[6];
  const float* proj_w = (const float*)d_in[7];
  const float* proj_b = (const float*)d_in[8];
  float* out = (float*)d_out;

  char* ws = (char*)d_ws;
  size_t off = 0;
  auto alloc = [&](size_t bytes) -> void* {
    void* p = ws + off;
    off += (bytes + 255) & ~(size_t)255;
    return p;
  };
  u16* x1b  = (u16*)alloc(8192ULL * 1024 * 2);
  u16* in_t = (u16*)alloc(8ULL * 1024 * 2048 * 2);
  u16* Wp   = (u16*)alloc(9ULL * 2097152 * 2);
  u16* wqb  = (u16*)alloc(1048576ULL * 2);
  u16* wkb  = (u16*)alloc(1048576ULL * 2);  // contiguous with wvb -> fused KV B
  u16* wvb  = (u16*)alloc(1048576ULL * 2);
  u16* pjb  = (u16*)alloc(1048576ULL * 2);
  u16* xc   = (u16*)alloc(8192ULL * 1024 * 2);
  u16* Qb   = (u16*)alloc(8192ULL * 1024 * 2);
  u16* Kb   = (u16*)alloc(8192ULL * 1024 * 2);
  u16* Vtb  = (u16*)alloc(8192ULL * 1024 * 2);
  u16* Ob   = (u16*)alloc(8192ULL * 1024 * 2);
  u16* zb   = (u16*)alloc(256);
  // split-K f32 partials (2 x 8192 x 1024 f32 = 64 MB) alias Qb..Ob (dead until Q GEMM)
  float* pConv = (float*)Qb;

  // prep
  cast4_k<<<dim3(1024, 4), 256, 0, stream>>>(wq, wk, wv, proj_w, wqb, wkb, wvb, pjb);
  build_int2<<<dim3(32, 16, 8), 256, 0, stream>>>(x1, x2, in_t, x1b);
  pack_wp<<<8192, 256, 0, stream>>>(conv_w, Wp);
  zero_k<<<1, 128, 0, stream>>>(zb);

  // conv as implicit GEMM, split-K x2 (each half K=9216), f32 partials
  gemm6_k<1><<<512, 256, 0, stream>>>(in_t, Wp, pConv, zb, 9216, 3);
  // combine partials + bias, transpose to xc[b][o][s]
  addc_k<<<dim3(16, 16, 8), 256, 0, stream>>>(pConv, conv_b, xc);
  // Q
  gemm3_k<GM_PLAIN><<<256, 512, 0, stream>>>(x1b, wqb, Qb, nullptr, nullptr, nullptr, 1024, 3);
  // fused K+V (B = [wk;wv] contiguous, N=2048), 512 blocks at 2/CU
  gemm5_k<GM_KV><<<512, 512, 0, stream>>>(xc, wkb, Kb, Vtb, zb, 1024, 4);
  // attention
  attn2_k<<<dim3(16, 64), 256, 0, stream>>>(Qb, Kb, Vtb, Ob);
  // projection + bias + residual (f32 out)
  gemm3_k<GM_PROJ><<<256, 512, 0, stream>>>(Ob, pjb, nullptr, out, proj_b, x1, 1024, 3);
}

// Round 8
// 564.317 us; speedup vs baseline: 1.0708x; 1.0166x over previous
//
#include <hip/hip_runtime.h>
#include <hip/hip_bf16.h>
#include <cstdint>
#include <cstddef>

typedef __attribute__((ext_vector_type(8))) short short8;
typedef __attribute__((ext_vector_type(4))) float f32x4;
typedef unsigned short u16;

static __device__ __forceinline__ u16 f2bf(float f) {
  __hip_bfloat16 h = __float2bfloat16(f);
  return *reinterpret_cast<u16*>(&h);
}

static __device__ __forceinline__ void gload16(const void* g, void* l) {
  __builtin_amdgcn_global_load_lds(
      (const __attribute__((address_space(1))) void*)g,
      (__attribute__((address_space(3))) void*)l, 16, 0, 0);
}

// ---------------- prep kernels ----------------

// all four weight casts in one dispatch
__global__ void cast4_k(const float* __restrict__ a, const float* __restrict__ b,
                        const float* __restrict__ c, const float* __restrict__ d,
                        u16* __restrict__ oa, u16* __restrict__ ob,
                        u16* __restrict__ oc, u16* __restrict__ od) {
  const int which = blockIdx.y;
  const float* src = (which == 0) ? a : (which == 1) ? b : (which == 2) ? c : d;
  u16* dst = (which == 0) ? oa : (which == 1) ? ob : (which == 2) ? oc : od;
  int i = blockIdx.x * 256 + threadIdx.x;   // 262144 float4 per tensor
  float4 v = ((const float4*)src)[i];
  union { u16 u[4]; uint2 p; } r;
  r.u[0] = f2bf(v.x); r.u[1] = f2bf(v.y); r.u[2] = f2bf(v.z); r.u[3] = f2bf(v.w);
  ((uint2*)dst)[i] = r.p;
}

// in_t_pad[(b*34 + y+1)*34 + x+1][i] = bf16( concat(x1,x2)[b][i][y*32+x] )
// (borders pre-zeroed by memset); also emits x1b = bf16(x1) flat
__global__ void build_pad(const float* __restrict__ x1, const float* __restrict__ x2,
                          u16* __restrict__ in_t_pad, u16* __restrict__ x1b) {
  __shared__ float tile[64][65];
  const int it = blockIdx.x;   // 32 i-tiles
  const int st = blockIdx.y;   // 16 s-tiles
  const int b  = blockIdx.z;   // 8
  const int i0 = it * 64, s0 = st * 64;
  const bool isx1 = (i0 < 1024);
  const float* src = isx1
      ? x1 + ((size_t)b * 1024 + i0) * 1024
      : x2 + ((size_t)b * 1024 + (i0 - 1024)) * 1024;
  const int t = threadIdx.x;
  #pragma unroll
  for (int jj = 0; jj < 16; ++jj) {
    int idx = jj * 256 + t;
    int ii = idx >> 6, si = idx & 63;
    float v = src[(size_t)ii * 1024 + s0 + si];
    tile[ii][si] = v;
    if (isx1)
      x1b[((size_t)b * 1024 + i0 + ii) * 1024 + s0 + si] = f2bf(v);
  }
  __syncthreads();
  #pragma unroll
  for (int jj = 0; jj < 16; ++jj) {
    int idx = jj * 256 + t;
    int si = idx >> 6, ii = idx & 63;
    const int s = s0 + si;
    const int prow = (b * 34 + (s >> 5) + 1) * 34 + (s & 31) + 1;
    in_t_pad[(size_t)prow * 2048 + i0 + ii] = f2bf(tile[ii][si]);
  }
}

// Wp[q][o][i] = bf16( conv_w[o][i][q] ),  q = ky*3+kx
__global__ void pack_wp(const float* __restrict__ cw, u16* __restrict__ Wp) {
  __shared__ float sb[2304];
  const int blk = blockIdx.x;  // 8192
  const int t = threadIdx.x;   // 256
  const size_t base = (size_t)blk * 2304;
  #pragma unroll
  for (int jj = 0; jj < 9; ++jj) sb[jj * 256 + t] = cw[base + jj * 256 + t];
  __syncthreads();
  const int p = blk * 256 + t;  // (o,i) linear
  #pragma unroll
  for (int q = 0; q < 9; ++q)
    Wp[(size_t)q * 2097152 + p] = f2bf(sb[t * 9 + q]);
}

// split-K combine: xc[b][o][s] = bf16(p0 + p1 + bias[o]); p is [kz][b*1024+s][o] f32
__global__ void addc_k(const float* __restrict__ p, const float* __restrict__ bias,
                       u16* __restrict__ xc) {
  __shared__ float tile[64][65];
  const int st = blockIdx.x;   // 16 s-tiles
  const int ot = blockIdx.y;   // 16 o-tiles
  const int b  = blockIdx.z;   // 8
  const int s0 = st * 64, o0 = ot * 64;
  const int t = threadIdx.x;
  const float* p1 = p + 8388608;
  #pragma unroll
  for (int jj = 0; jj < 16; ++jj) {
    int idx = jj * 256 + t;
    int si = idx >> 6, oi = idx & 63;
    const size_t m = ((size_t)b * 1024 + s0 + si) * 1024 + o0 + oi;
    tile[si][oi] = p[m] + p1[m] + bias[o0 + oi];
  }
  __syncthreads();
  #pragma unroll
  for (int jj = 0; jj < 16; ++jj) {
    int idx = jj * 256 + t;
    int oi = idx >> 6, si = idx & 63;
    xc[((size_t)b * 1024 + o0 + oi) * 1024 + s0 + si] = f2bf(tile[si][oi]);
  }
}

enum { GM_PLAIN = 0, GM_PROJ = 2, GM_KV = 4 };

// ---------------- conv GEMM with A-halo reuse: 256x128 tile, 4 waves ----------------
// Per 32-ch chunk: stage 384-row padded A-halo ONCE (24 KB, dbuf), then 9 planes
// each stage only B (8 KB, 3-buf) -> staged bytes/FLOP cut 2.25x vs r6.
// vmcnt ledger (per-wave load units: halo=6, B=2), order {wait,barrier,stage,compute}:
//   vmcnt(8) @ q in {1,2} of interior cc; vmcnt(0) @ last plane; else vmcnt(2).
__global__ __launch_bounds__(256, 2)
void conv7_k(const u16* __restrict__ Ap, const u16* __restrict__ B,
             float* __restrict__ Cf) {
  __shared__ u16 lds[2 * 12288 + 3 * 4096];   // 2 A-halos (24KB) + 3 B bufs (8KB)
  const int tid = threadIdx.x;
  const int lane = tid & 63, w = tid >> 6;
  const int l15 = lane & 15, l4 = lane >> 4;

  // T1 XCD remap, grid 512 (2 kz x 256 tiles)
  const int bid = blockIdx.x;
  const int lb = (bid & 7) * 64 + (bid >> 3);
  const int kz = lb >> 8;
  const int tile = lb & 255;
  const int tm = tile >> 3, tn = tile & 7;
  const int row0 = tm * 256, col0 = tn * 128;
  const int b = tm >> 2;
  const int y0 = (tm & 3) * 8;
  const int hb = (b * 34 + y0) * 34;       // halo base pad-row
  const int wr = w * 64;
  const int chbase = kz * 1024;

  // per-thread A-frag pad-row offsets (relative to hb), before plane shift
  int pr[4];
  #pragma unroll
  for (int mi = 0; mi < 4; ++mi) {
    const int m = row0 + wr + mi * 16 + l15;
    const int y = (m >> 5) & 31, x = m & 31;
    pr[mi] = (y - y0 + 1) * 34 + x + 1;    // in [35, 304]; +dd stays in [0,340)
  }

  // staging geometry
  const int srow = tid >> 2;   // 0..63
  const int sgc = tid & 3;

  f32x4 acc[4][8];
  #pragma unroll
  for (int i = 0; i < 4; ++i)
    #pragma unroll
    for (int jj = 0; jj < 8; ++jj)
      acc[i][jj] = (f32x4){0.f, 0.f, 0.f, 0.f};

  auto stageHalo = [&](int cc, int half) {   // 6 loads/thread
    u16* dst = lds + half * 12288;
    #pragma unroll
    for (int rnd = 0; rnd < 6; ++rnd) {
      const int row = rnd * 64 + srow;       // 0..383
      const int g = sgc ^ ((row >> 1) & 3);
      const u16* src = Ap + (size_t)(hb + row) * 2048 + chbase + cc * 32 + g * 8;
      gload16(src, dst + (size_t)(rnd * 256 + tid) * 8);
    }
  };
  auto stageB = [&](int cc, int q) {         // 2 loads/thread
    u16* dst = lds + 24576 + (q % 3) * 4096;
    #pragma unroll
    for (int rnd = 0; rnd < 2; ++rnd) {
      const int r = rnd * 64 + srow;         // 0..127
      const int g = sgc ^ ((r >> 1) & 3);
      const u16* src = B + ((size_t)q << 21) + (size_t)(col0 + r) * 2048
                       + chbase + cc * 32 + g * 8;
      gload16(src, dst + (size_t)(rnd * 256 + tid) * 8);
    }
  };

  constexpr int ddt[9] = {-35, -34, -33, -1, 0, 1, 33, 34, 35};
  constexpr int NC = 32;

  // prologue: halo(0), halo(1), B[0], B[1]
  stageHalo(0, 0);
  stageHalo(1, 1);
  stageB(0, 0);
  stageB(0, 1);

  for (int cc = 0; cc < NC; ++cc) {
    const u16* hcur = lds + (cc & 1) * 12288;
    const bool interior = (cc >= 1 && cc <= NC - 2);
    #pragma unroll
    for (int q = 0; q < 9; ++q) {
      // ---- wait + barrier ----
      if ((q == 1 || q == 2) && interior) {
        asm volatile("s_waitcnt vmcnt(8)" ::: "memory");
      } else if (q == 8 && cc == NC - 1) {
        asm volatile("s_waitcnt vmcnt(0)" ::: "memory");
      } else {
        asm volatile("s_waitcnt vmcnt(2)" ::: "memory");
      }
      __builtin_amdgcn_s_barrier();
      // ---- stage (after barrier: all waves done with the buffers we overwrite) ----
      {
        const int gp2 = cc * 9 + q + 2;
        if (gp2 <= NC * 9 - 1) {
          int qS = q + 2, ccS = cc;
          if (qS >= 9) { qS -= 9; ccS += 1; }
          stageB(ccS, qS);
        }
        if (q == 0 && cc >= 1 && cc <= NC - 2)
          stageHalo(cc + 1, (cc + 1) & 1);
      }
      // ---- compute plane q ----
      {
        const u16* bq = lds + 24576 + (q % 3) * 4096;
        const int dd = ddt[q];
        short8 av[4], bv[8];
        #pragma unroll
        for (int mi = 0; mi < 4; ++mi) {
          const int hr = pr[mi] + dd;
          const int g = l4 ^ ((hr >> 1) & 3);
          av[mi] = *(const short8*)(hcur + hr * 32 + g * 8);
        }
        #pragma unroll
        for (int ni = 0; ni < 8; ++ni) {
          const int r = ni * 16 + l15;
          const int g = l4 ^ ((r >> 1) & 3);
          bv[ni] = *(const short8*)(bq + r * 32 + g * 8);
        }
        __builtin_amdgcn_s_setprio(1);
        #pragma unroll
        for (int mi = 0; mi < 4; ++mi)
          #pragma unroll
          for (int ni = 0; ni < 8; ++ni)
            acc[mi][ni] = __builtin_amdgcn_mfma_f32_16x16x32_bf16(av[mi], bv[ni], acc[mi][ni], 0, 0, 0);
        __builtin_amdgcn_s_setprio(0);
      }
    }
  }

  // epilogue: f32 partials, layout [kz][m][o]
  #pragma unroll
  for (int mi = 0; mi < 4; ++mi) {
    #pragma unroll
    for (int ni = 0; ni < 8; ++ni) {
      #pragma unroll
      for (int j = 0; j < 4; ++j) {
        const int grow = row0 + wr + mi * 16 + l4 * 4 + j;
        const int gcol = col0 + ni * 16 + l15;
        Cf[(size_t)kz * 8388608 + ((size_t)grow << 10) + gcol] = acc[mi][ni][j];
      }
    }
  }
}

// ---------------- GEMM A: 256x128 tile, BK=64, triple-buffer 144KB ----------------
template<int MODE>
__global__ __launch_bounds__(512, 2)
void gemm3_k(const u16* __restrict__ A, const u16* __restrict__ B,
             u16* __restrict__ Cb, float* __restrict__ Cf,
             const float* __restrict__ bias, const float* __restrict__ resid,
             int Ktot, int ntn_sh) {
  __shared__ u16 lds[3 * 24576];
  const int tid = threadIdx.x;
  const int lane = tid & 63;
  const int w = tid >> 6;
  const int l15 = lane & 15, l4 = lane >> 4;

  const int nwg = gridDim.x;
  const int bid = blockIdx.x;
  const int lb = (bid & 7) * (nwg >> 3) + (bid >> 3);
  const int tm = lb >> ntn_sh;
  const int tn = lb & ((1 << ntn_sh) - 1);
  const int row0 = tm * 256, col0 = tn * 128;
  const int wr = (w >> 1) * 64, wc = (w & 1) * 64;

  const int sr = w * 8 + (lane >> 3);
  const int pp = (lane & 7) ^ (lane >> 3);

  f32x4 acc[4][4];
  #pragma unroll
  for (int i = 0; i < 4; ++i)
    #pragma unroll
    for (int jj = 0; jj < 4; ++jj)
      acc[i][jj] = (f32x4){0.f, 0.f, 0.f, 0.f};

  const int nK = Ktot >> 6;

  auto stage = [&](int kt, u16* buf) {
    u16* da = buf + (size_t)w * 512;
    u16* db = buf + 16384 + (size_t)w * 512;
    const int k0 = kt << 6;
    #pragma unroll
    for (int u = 0; u < 4; ++u) {
      const u16* ga = A + (size_t)(row0 + u * 64 + sr) * Ktot + k0 + pp * 8;
      gload16(ga, da + u * 4096);
    }
    #pragma unroll
    for (int u = 0; u < 2; ++u) {
      const u16* gb = B + (size_t)(col0 + u * 64 + sr) * Ktot + k0 + pp * 8;
      gload16(gb, db + u * 4096);
    }
  };

  auto compute = [&](const u16* buf) {
    const char* Ar = (const char*)buf;
    const char* Br = (const char*)(buf + 16384);
    #pragma unroll
    for (int ks = 0; ks < 2; ++ks) {
      const int bcol = ((ks << 6) + (l4 << 4)) ^ ((l15 & 7) << 4);
      short8 av[4], bv[4];
      #pragma unroll
      for (int mi = 0; mi < 4; ++mi)
        av[mi] = *(const short8*)(Ar + (wr + mi * 16 + l15) * 128 + bcol);
      #pragma unroll
      for (int ni = 0; ni < 4; ++ni)
        bv[ni] = *(const short8*)(Br + (wc + ni * 16 + l15) * 128 + bcol);
      __builtin_amdgcn_s_setprio(1);
      #pragma unroll
      for (int mi = 0; mi < 4; ++mi)
        #pragma unroll
        for (int ni = 0; ni < 4; ++ni)
          acc[mi][ni] = __builtin_amdgcn_mfma_f32_16x16x32_bf16(av[mi], bv[ni], acc[mi][ni], 0, 0, 0);
      __builtin_amdgcn_s_setprio(0);
    }
  };

  u16* pb0 = lds;
  u16* pb1 = lds + 24576;
  u16* pb2 = lds + 49152;

  stage(0, pb0);
  stage(1, pb1);
  for (int t = 0; t < nK; ++t) {
    if (t + 1 < nK) {
      asm volatile("s_waitcnt vmcnt(6)" ::: "memory");
    } else {
      asm volatile("s_waitcnt vmcnt(0)" ::: "memory");
    }
    __builtin_amdgcn_s_barrier();
    if (t + 2 < nK) stage(t + 2, pb2);
    compute(pb0);
    u16* tmp = pb0; pb0 = pb1; pb1 = pb2; pb2 = tmp;
  }

  #pragma unroll
  for (int mi = 0; mi < 4; ++mi) {
    #pragma unroll
    for (int ni = 0; ni < 4; ++ni) {
      #pragma unroll
      for (int j = 0; j < 4; ++j) {
        const int grow = row0 + wr + mi * 16 + l4 * 4 + j;
        const int gcol = col0 + wc + ni * 16 + l15;
        const float v = acc[mi][ni][j];
        if constexpr (MODE == GM_PLAIN) {
          Cb[((size_t)grow << 10) + gcol] = f2bf(v);
        } else if constexpr (MODE == GM_PROJ) {
          const size_t o = ((size_t)grow << 10) + gcol;
          Cf[o] = v + bias[gcol] + resid[o];
        }
      }
    }
  }
}

// ---------------- GEMM B: 256x128 tile, BK=32, 8 waves, 72KB -> 2 blocks/CU ----------------
template<int MODE>
__global__ __launch_bounds__(512, 4)
void gemm5_k(const u16* __restrict__ A, const u16* __restrict__ B,
             u16* __restrict__ Cb, u16* __restrict__ Cb2,
             int Ktot, int ntn_sh) {
  __shared__ u16 lds[3 * 12288];
  const int tid = threadIdx.x;
  const int lane = tid & 63;
  const int w = tid >> 6;
  const int l15 = lane & 15, l4 = lane >> 4;

  const int nwg = gridDim.x;
  const int bid = blockIdx.x;
  const int lb = (bid & 7) * (nwg >> 3) + (bid >> 3);
  const int tm = lb >> ntn_sh;
  const int tn = lb & ((1 << ntn_sh) - 1);
  const int row0 = tm * 256, col0 = tn * 128;
  const int wr = (w >> 1) * 64, wc = (w & 1) * 64;

  const int str = tid >> 2;       // 0..127
  const int sgc = tid & 3;

  f32x4 acc[4][4];
  #pragma unroll
  for (int i = 0; i < 4; ++i)
    #pragma unroll
    for (int jj = 0; jj < 4; ++jj)
      acc[i][jj] = (f32x4){0.f, 0.f, 0.f, 0.f};

  const int nKt = Ktot >> 5;

  auto stage = [&](int kt, u16* buf) {
    const int k0 = kt << 5;
    #pragma unroll
    for (int u = 0; u < 2; ++u) {
      const int r = u * 128 + str;
      const int swz = sgc ^ ((r >> 1) & 3);
      const u16* ga = A + (size_t)(row0 + r) * Ktot + k0 + swz * 8;
      gload16(ga, buf + ((size_t)u * 512 + tid) * 8);
    }
    {
      const int swz = sgc ^ ((str >> 1) & 3);
      const u16* gb = B + (size_t)(col0 + str) * Ktot + k0 + swz * 8;
      gload16(gb, buf + 8192 + (size_t)tid * 8);
    }
  };

  auto compute = [&](const u16* buf) {
    short8 av[4], bv[4];
    #pragma unroll
    for (int mi = 0; mi < 4; ++mi) {
      const int row = wr + mi * 16 + l15;
      const int g = l4 ^ ((row >> 1) & 3);
      av[mi] = *(const short8*)(buf + row * 32 + g * 8);
    }
    #pragma unroll
    for (int ni = 0; ni < 4; ++ni) {
      const int row = wc + ni * 16 + l15;
      const int g = l4 ^ ((row >> 1) & 3);
      bv[ni] = *(const short8*)(buf + 8192 + row * 32 + g * 8);
    }
    __builtin_amdgcn_s_setprio(1);
    #pragma unroll
    for (int mi = 0; mi < 4; ++mi)
      #pragma unroll
      for (int ni = 0; ni < 4; ++ni)
        acc[mi][ni] = __builtin_amdgcn_mfma_f32_16x16x32_bf16(av[mi], bv[ni], acc[mi][ni], 0, 0, 0);
    __builtin_amdgcn_s_setprio(0);
  };

  u16* pb0 = lds;
  u16* pb1 = lds + 12288;
  u16* pb2 = lds + 24576;

  stage(0, pb0);
  stage(1, pb1);
  for (int t = 0; t < nKt; ++t) {
    if (t + 1 < nKt) {
      asm volatile("s_waitcnt vmcnt(3)" ::: "memory");
    } else {
      asm volatile("s_waitcnt vmcnt(0)" ::: "memory");
    }
    __builtin_amdgcn_s_barrier();
    if (t + 2 < nKt) stage(t + 2, pb2);
    compute(pb0);
    u16* tmp = pb0; pb0 = pb1; pb1 = pb2; pb2 = tmp;
  }

  #pragma unroll
  for (int mi = 0; mi < 4; ++mi) {
    #pragma unroll
    for (int ni = 0; ni < 4; ++ni) {
      #pragma unroll
      for (int j = 0; j < 4; ++j) {
        const int grow = row0 + wr + mi * 16 + l4 * 4 + j;
        const int gcol = col0 + wc + ni * 16 + l15;
        const float v = acc[mi][ni][j];
        if constexpr (MODE == GM_KV) {
          if (gcol < 1024) {
            Cb[((size_t)grow << 10) + gcol] = f2bf(v);
          } else {
            const int c = gcol - 1024;
            const int b = grow >> 10, ms = grow & 1023;
            const int h = c >> 7, d = c & 127;
            Cb2[((size_t)((b * 8 + h) * 128 + d) << 10) + ms] = f2bf(v);
          }
        }
      }
    }
  }
}

// ---------------- flash attention (double-buffered, 1 barrier/iter) ----------------
__global__ __launch_bounds__(256, 2)
void attn2_k(const u16* __restrict__ Q, const u16* __restrict__ K,
             const u16* __restrict__ Vt, u16* __restrict__ O) {
  __shared__ u16 Ks[2][64 * 128];
  __shared__ u16 Vs[2][128 * 64];
  __shared__ u16 Plds[4][16 * 80];
  const int mtile = blockIdx.x;
  const int bh = blockIdx.y;
  const int b = bh >> 3, h = bh & 7;
  const int tid = threadIdx.x, lane = tid & 63, w = tid >> 6;
  const int l15 = lane & 15, l4 = lane >> 4;

  short8 qf[4];
  {
    const int qrow = b * 1024 + mtile * 64 + w * 16 + l15;
    const u16* qb = Q + ((size_t)qrow << 10) + h * 128;
    #pragma unroll
    for (int kk = 0; kk < 4; ++kk)
      qf[kk] = *(const short8*)(qb + kk * 32 + l4 * 8);
  }

  f32x4 o[8];
  #pragma unroll
  for (int db = 0; db < 8; ++db) o[db] = (f32x4){0.f, 0.f, 0.f, 0.f};
  float mrow[4], lrow[4];
  #pragma unroll
  for (int j = 0; j < 4; ++j) { mrow[j] = -1e30f; lrow[j] = 0.f; }
  const float scale = 0.08838834764831845f;  // 128^-0.5

  auto stageKV = [&](int kt, int half) {
    #pragma unroll
    for (int j = 0; j < 4; ++j) {
      const int c = (j * 4 + w) * 64 + lane;
      const int r = c >> 4;
      const int coff = (((c & 15) ^ (r & 7)) << 3);
      const u16* gp = K + ((size_t)(b * 1024 + kt * 64 + r) << 10) + h * 128 + coff;
      gload16(gp, (void*)(Ks[half] + (j * 4 + w) * 512));
    }
    #pragma unroll
    for (int j = 0; j < 4; ++j) {
      const int c = (j * 4 + w) * 64 + lane;
      const int r = c >> 3;
      const int coff = (((c & 7) ^ (r & 7)) << 3);
      const u16* gp = Vt + ((size_t)((b * 8 + h) * 128 + r) << 10) + kt * 64 + coff;
      gload16(gp, (void*)(Vs[half] + (j * 4 + w) * 512));
    }
  };

  stageKV(0, 0);
  for (int kt = 0; kt < 16; ++kt) {
    const int cur = kt & 1;
    asm volatile("s_waitcnt vmcnt(0)" ::: "memory");
    __builtin_amdgcn_s_barrier();
    if (kt + 1 < 16) stageKV(kt + 1, cur ^ 1);

    const u16* ks_ = Ks[cur];
    const u16* vs_ = Vs[cur];
    f32x4 s[4];
    #pragma unroll
    for (int cb = 0; cb < 4; ++cb) {
      s[cb] = (f32x4){0.f, 0.f, 0.f, 0.f};
      #pragma unroll
      for (int kk = 0; kk < 4; ++kk) {
        const int col = (kk * 32 + l4 * 8) ^ ((l15 & 7) << 3);
        short8 bK = *(const short8*)(ks_ + (cb * 16 + l15) * 128 + col);
        s[cb] = __builtin_amdgcn_mfma_f32_16x16x32_bf16(qf[kk], bK, s[cb], 0, 0, 0);
      }
    }
    #pragma unroll
    for (int cb = 0; cb < 4; ++cb) {
      s[cb][0] *= scale; s[cb][1] *= scale; s[cb][2] *= scale; s[cb][3] *= scale;
    }
    #pragma unroll
    for (int j = 0; j < 4; ++j) {
      float mx = fmaxf(fmaxf(s[0][j], s[1][j]), fmaxf(s[2][j], s[3][j]));
      #pragma unroll
      for (int off = 8; off >= 1; off >>= 1)
        mx = fmaxf(mx, __shfl_xor(mx, off, 64));
      const float mn = fmaxf(mrow[j], mx);
      const float fac = __expf(mrow[j] - mn);
      mrow[j] = mn;
      float rs = 0.f;
      #pragma unroll
      for (int cb = 0; cb < 4; ++cb) {
        const float p = __expf(s[cb][j] - mn);
        s[cb][j] = p;
        rs += p;
      }
      #pragma unroll
      for (int off = 8; off >= 1; off >>= 1)
        rs += __shfl_xor(rs, off, 64);
      lrow[j] = lrow[j] * fac + rs;
      #pragma unroll
      for (int db = 0; db < 8; ++db) o[db][j] *= fac;
    }
    u16* pl = Plds[w];
    #pragma unroll
    for (int cb = 0; cb < 4; ++cb)
      #pragma unroll
      for (int j = 0; j < 4; ++j)
        pl[(l4 * 4 + j) * 80 + cb * 16 + l15] = f2bf(s[cb][j]);
    asm volatile("s_waitcnt lgkmcnt(0)" ::: "memory");
    __builtin_amdgcn_sched_barrier(0);
    short8 ap[2];
    #pragma unroll
    for (int ks2 = 0; ks2 < 2; ++ks2)
      ap[ks2] = *(const short8*)(pl + l15 * 80 + ks2 * 32 + l4 * 8);
    #pragma unroll
    for (int db = 0; db < 8; ++db) {
      #pragma unroll
      for (int ks2 = 0; ks2 < 2; ++ks2) {
        const int col = (ks2 * 32 + l4 * 8) ^ ((l15 & 7) << 3);
        short8 bV = *(const short8*)(vs_ + (db * 16 + l15) * 64 + col);
        o[db] = __builtin_amdgcn_mfma_f32_16x16x32_bf16(ap[ks2], bV, o[db], 0, 0, 0);
      }
    }
  }
  #pragma unroll
  for (int db = 0; db < 8; ++db) {
    #pragma unroll
    for (int j = 0; j < 4; ++j) {
      const int grow = b * 1024 + mtile * 64 + w * 16 + l4 * 4 + j;
      const int gcol = h * 128 + db * 16 + l15;
      O[((size_t)grow << 10) + gcol] = f2bf(o[db][j] / lrow[j]);
    }
  }
}

// ---------------- launch ----------------

extern "C" void kernel_launch(void* const* d_in, const int* in_sizes, int n_in,
                              void* d_out, int out_size, void* d_ws, size_t ws_size,
                              hipStream_t stream) {
  const float* x1     = (const float*)d_in[0];
  const float* x2     = (const float*)d_in[1];
  const float* conv_w = (const float*)d_in[2];
  const float* conv_b = (const float*)d_in[3];
  const float* wq     = (const float*)d_in[4];
  const float* wk     = (const float*)d_in[5];
  const float* wv     = (const float*)d_in[6];
  const float* proj_w = (const float*)d_in[7];
  const float* proj_b = (const float*)d_in[8];
  float* out = (float*)d_out;

  char* ws = (char*)d_ws;
  size_t off = 0;
  auto alloc = [&](size_t bytes) -> void* {
    void* p = ws + off;
    off += (bytes + 255) & ~(size_t)255;
    return p;
  };
  u16* x1b  = (u16*)alloc(8192ULL * 1024 * 2);
  // padded input: 8 b x 34 x 34 pad-rows x 2048 ch (+96 slack rows for halo overrun)
  u16* in_t_pad = (u16*)alloc((9248ULL + 96) * 2048 * 2);
  const size_t pad_bytes = 9248ULL * 2048 * 2;
  u16* Wp   = (u16*)alloc(9ULL * 2097152 * 2);
  u16* wqb  = (u16*)alloc(1048576ULL * 2);
  u16* wkb  = (u16*)alloc(1048576ULL * 2);  // contiguous with wvb -> fused KV B
  u16* wvb  = (u16*)alloc(1048576ULL * 2);
  u16* pjb  = (u16*)alloc(1048576ULL * 2);
  u16* xc   = (u16*)alloc(8192ULL * 1024 * 2);
  u16* Qb   = (u16*)alloc(8192ULL * 1024 * 2);
  u16* Kb   = (u16*)alloc(8192ULL * 1024 * 2);
  u16* Vtb  = (u16*)alloc(8192ULL * 1024 * 2);
  u16* Ob   = (u16*)alloc(8192ULL * 1024 * 2);
  // split-K f32 partials (2 x 8192 x 1024 f32 = 64 MB) alias Qb..Ob (dead until Q GEMM)
  float* pConv = (float*)Qb;

  // prep
  (void)hipMemsetAsync(in_t_pad, 0, pad_bytes + 96ULL * 2048 * 2, stream);
  cast4_k<<<dim3(1024, 4), 256, 0, stream>>>(wq, wk, wv, proj_w, wqb, wkb, wvb, pjb);
  build_pad<<<dim3(32, 16, 8), 256, 0, stream>>>(x1, x2, in_t_pad, x1b);
  pack_wp<<<8192, 256, 0, stream>>>(conv_w, Wp);

  // conv: halo-reuse implicit GEMM, split-K x2 (kz = channel half), f32 partials
  conv7_k<<<512, 256, 0, stream>>>(in_t_pad, Wp, pConv);
  // combine partials + bias, transpose to xc[b][o][s]
  addc_k<<<dim3(16, 16, 8), 256, 0, stream>>>(pConv, conv_b, xc);
  // Q
  gemm3_k<GM_PLAIN><<<256, 512, 0, stream>>>(x1b, wqb, Qb, nullptr, nullptr, nullptr, 1024, 3);
  // fused K+V (B = [wk;wv] contiguous, N=2048), 512 blocks at 2/CU
  gemm5_k<GM_KV><<<512, 512, 0, stream>>>(xc, wkb, Kb, Vtb, 1024, 4);
  // attention
  attn2_k<<<dim3(16, 64), 256, 0, stream>>>(Qb, Kb, Vtb, Ob);
  // projection + bias + residual (f32 out)
  gemm3_k<GM_PROJ><<<256, 512, 0, stream>>>(Ob, pjb, nullptr, out, proj_b, x1, 1024, 3);
}

// Round 9
// 555.571 us; speedup vs baseline: 1.0877x; 1.0157x over previous
//
#include <hip/hip_runtime.h>
#include <hip/hip_bf16.h>
#include <cstdint>
#include <cstddef>

typedef __attribute__((ext_vector_type(8))) short short8;
typedef __attribute__((ext_vector_type(4))) float f32x4;
typedef __attribute__((ext_vector_type(16))) float f32x16;
typedef unsigned short u16;

static __device__ __forceinline__ u16 f2bf(float f) {
  __hip_bfloat16 h = __float2bfloat16(f);
  return *reinterpret_cast<u16*>(&h);
}

static __device__ __forceinline__ void gload16(const void* g, void* l) {
  __builtin_amdgcn_global_load_lds(
      (const __attribute__((address_space(1))) void*)g,
      (__attribute__((address_space(3))) void*)l, 16, 0, 0);
}

// ---------------- prep kernels ----------------

__global__ void cast4_k(const float* __restrict__ a, const float* __restrict__ b,
                        const float* __restrict__ c, const float* __restrict__ d,
                        u16* __restrict__ oa, u16* __restrict__ ob,
                        u16* __restrict__ oc, u16* __restrict__ od) {
  const int which = blockIdx.y;
  const float* src = (which == 0) ? a : (which == 1) ? b : (which == 2) ? c : d;
  u16* dst = (which == 0) ? oa : (which == 1) ? ob : (which == 2) ? oc : od;
  int i = blockIdx.x * 256 + threadIdx.x;
  float4 v = ((const float4*)src)[i];
  union { u16 u[4]; uint2 p; } r;
  r.u[0] = f2bf(v.x); r.u[1] = f2bf(v.y); r.u[2] = f2bf(v.z); r.u[3] = f2bf(v.w);
  ((uint2*)dst)[i] = r.p;
}

// in_t_pad[(b*34 + y+1)*34 + x+1][i] = bf16( concat(x1,x2)[b][i][y*32+x] )
__global__ void build_pad(const float* __restrict__ x1, const float* __restrict__ x2,
                          u16* __restrict__ in_t_pad, u16* __restrict__ x1b) {
  __shared__ float tile[64][65];
  const int it = blockIdx.x;
  const int st = blockIdx.y;
  const int b  = blockIdx.z;
  const int i0 = it * 64, s0 = st * 64;
  const bool isx1 = (i0 < 1024);
  const float* src = isx1
      ? x1 + ((size_t)b * 1024 + i0) * 1024
      : x2 + ((size_t)b * 1024 + (i0 - 1024)) * 1024;
  const int t = threadIdx.x;
  #pragma unroll
  for (int jj = 0; jj < 16; ++jj) {
    int idx = jj * 256 + t;
    int ii = idx >> 6, si = idx & 63;
    float v = src[(size_t)ii * 1024 + s0 + si];
    tile[ii][si] = v;
    if (isx1)
      x1b[((size_t)b * 1024 + i0 + ii) * 1024 + s0 + si] = f2bf(v);
  }
  __syncthreads();
  #pragma unroll
  for (int jj = 0; jj < 16; ++jj) {
    int idx = jj * 256 + t;
    int si = idx >> 6, ii = idx & 63;
    const int s = s0 + si;
    const int prow = (b * 34 + (s >> 5) + 1) * 34 + (s & 31) + 1;
    in_t_pad[(size_t)prow * 2048 + i0 + ii] = f2bf(tile[ii][si]);
  }
}

// Wp[q][o][i] = bf16( conv_w[o][i][q] ),  q = ky*3+kx
__global__ void pack_wp(const float* __restrict__ cw, u16* __restrict__ Wp) {
  __shared__ float sb[2304];
  const int blk = blockIdx.x;
  const int t = threadIdx.x;
  const size_t base = (size_t)blk * 2304;
  #pragma unroll
  for (int jj = 0; jj < 9; ++jj) sb[jj * 256 + t] = cw[base + jj * 256 + t];
  __syncthreads();
  const int p = blk * 256 + t;
  #pragma unroll
  for (int q = 0; q < 9; ++q)
    Wp[(size_t)q * 2097152 + p] = f2bf(sb[t * 9 + q]);
}

// split-K combine: xc[b][o][s] = bf16(p0 + p1 + bias[o]); p is [kz][b*1024+s][o] f32
__global__ void addc_k(const float* __restrict__ p, const float* __restrict__ bias,
                       u16* __restrict__ xc) {
  __shared__ float tile[64][65];
  const int st = blockIdx.x;
  const int ot = blockIdx.y;
  const int b  = blockIdx.z;
  const int s0 = st * 64, o0 = ot * 64;
  const int t = threadIdx.x;
  const float* p1 = p + 8388608;
  #pragma unroll
  for (int jj = 0; jj < 16; ++jj) {
    int idx = jj * 256 + t;
    int si = idx >> 6, oi = idx & 63;
    const size_t m = ((size_t)b * 1024 + s0 + si) * 1024 + o0 + oi;
    tile[si][oi] = p[m] + p1[m] + bias[o0 + oi];
  }
  __syncthreads();
  #pragma unroll
  for (int jj = 0; jj < 16; ++jj) {
    int idx = jj * 256 + t;
    int oi = idx >> 6, si = idx & 63;
    xc[((size_t)b * 1024 + o0 + oi) * 1024 + s0 + si] = f2bf(tile[si][oi]);
  }
}

enum { GM_PLAIN = 0, GM_PROJ = 2, GM_KV = 4 };

// ---------------- conv GEMM: halo reuse + 32x32x16 MFMA ----------------
// 256x128 tile, 4 waves, wave tile 64x128 as 2x4 tiles of 32x32.
// A/B frag: idx=lane&31, k=8*(lane>>5)+e; C/D: col=lane&31, row=(r&3)+8*(r>>2)+4*(lane>>5).
__global__ __launch_bounds__(256, 2)
void conv8_k(const u16* __restrict__ Ap, const u16* __restrict__ B,
             float* __restrict__ Cf) {
  __shared__ u16 lds[2 * 12288 + 3 * 4096];   // 2 A-halos (24KB) + 3 B bufs (8KB)
  const int tid = threadIdx.x;
  const int lane = tid & 63, w = tid >> 6;
  const int l31 = lane & 31, l1 = lane >> 5;

  // T1 XCD remap, grid 512 (2 kz x 256 tiles)
  const int bid = blockIdx.x;
  const int lb = (bid & 7) * 64 + (bid >> 3);
  const int kz = lb >> 8;
  const int tile = lb & 255;
  const int tm = tile >> 3, tn = tile & 7;
  const int row0 = tm * 256, col0 = tn * 128;
  const int b = tm >> 2;
  const int y0 = (tm & 3) * 8;
  const int hb = (b * 34 + y0) * 34;       // halo base pad-row
  const int wr = w * 64;
  const int chbase = kz * 1024;

  // per-thread A-frag pad-row offsets (mi row-blocks of 32)
  int pr[2];
  #pragma unroll
  for (int mi = 0; mi < 2; ++mi) {
    const int m = row0 + wr + mi * 32 + l31;
    const int y = (m >> 5) & 31, x = m & 31;
    pr[mi] = (y - y0 + 1) * 34 + x + 1;
  }

  const int srow = tid >> 2;   // 0..63
  const int sgc = tid & 3;

  f32x16 acc[2][4];
  #pragma unroll
  for (int i = 0; i < 2; ++i)
    #pragma unroll
    for (int jj = 0; jj < 4; ++jj)
      #pragma unroll
      for (int r = 0; r < 16; ++r)
        acc[i][jj][r] = 0.f;

  auto stageHalo = [&](int cc, int half) {   // 6 loads/thread
    u16* dst = lds + half * 12288;
    #pragma unroll
    for (int rnd = 0; rnd < 6; ++rnd) {
      const int row = rnd * 64 + srow;
      const int g = sgc ^ ((row >> 1) & 3);
      const u16* src = Ap + (size_t)(hb + row) * 2048 + chbase + cc * 32 + g * 8;
      gload16(src, dst + (size_t)(rnd * 256 + tid) * 8);
    }
  };
  auto stageB = [&](int cc, int q) {         // 2 loads/thread
    u16* dst = lds + 24576 + (q % 3) * 4096;
    #pragma unroll
    for (int rnd = 0; rnd < 2; ++rnd) {
      const int r = rnd * 64 + srow;
      const int g = sgc ^ ((r >> 1) & 3);
      const u16* src = B + ((size_t)q << 21) + (size_t)(col0 + r) * 2048
                       + chbase + cc * 32 + g * 8;
      gload16(src, dst + (size_t)(rnd * 256 + tid) * 8);
    }
  };

  constexpr int ddt[9] = {-35, -34, -33, -1, 0, 1, 33, 34, 35};
  constexpr int NC = 32;

  stageHalo(0, 0);
  stageHalo(1, 1);
  stageB(0, 0);
  stageB(0, 1);

  for (int cc = 0; cc < NC; ++cc) {
    const u16* hcur = lds + (cc & 1) * 12288;
    const bool interior = (cc >= 1 && cc <= NC - 2);
    #pragma unroll
    for (int q = 0; q < 9; ++q) {
      // ---- wait + barrier ----
      if ((q == 1 || q == 2) && interior) {
        asm volatile("s_waitcnt vmcnt(8)" ::: "memory");
      } else if (q == 8 && cc == NC - 1) {
        asm volatile("s_waitcnt vmcnt(0)" ::: "memory");
      } else {
        asm volatile("s_waitcnt vmcnt(2)" ::: "memory");
      }
      __builtin_amdgcn_s_barrier();
      // ---- stage ----
      {
        const int gp2 = cc * 9 + q + 2;
        if (gp2 <= NC * 9 - 1) {
          int qS = q + 2, ccS = cc;
          if (qS >= 9) { qS -= 9; ccS += 1; }
          stageB(ccS, qS);
        }
        if (q == 0 && cc >= 1 && cc <= NC - 2)
          stageHalo(cc + 1, (cc + 1) & 1);
      }
      // ---- compute plane q (K=32 as two K=16 steps) ----
      {
        const u16* bq = lds + 24576 + (q % 3) * 4096;
        const int dd = ddt[q];
        short8 av[2][2], bv[2][4];
        #pragma unroll
        for (int k = 0; k < 2; ++k) {
          const int g0 = k * 2 + l1;         // 16B granule of k-range
          #pragma unroll
          for (int mi = 0; mi < 2; ++mi) {
            const int hr = pr[mi] + dd;
            const int g = g0 ^ ((hr >> 1) & 3);
            av[k][mi] = *(const short8*)(hcur + hr * 32 + g * 8);
          }
          #pragma unroll
          for (int ni = 0; ni < 4; ++ni) {
            const int r = ni * 32 + l31;
            const int g = g0 ^ ((r >> 1) & 3);
            bv[k][ni] = *(const short8*)(bq + r * 32 + g * 8);
          }
        }
        __builtin_amdgcn_s_setprio(1);
        #pragma unroll
        for (int k = 0; k < 2; ++k)
          #pragma unroll
          for (int mi = 0; mi < 2; ++mi)
            #pragma unroll
            for (int ni = 0; ni < 4; ++ni)
              acc[mi][ni] = __builtin_amdgcn_mfma_f32_32x32x16_bf16(av[k][mi], bv[k][ni], acc[mi][ni], 0, 0, 0);
        __builtin_amdgcn_s_setprio(0);
      }
    }
  }

  // epilogue: f32 partials [kz][m][o]; D row=(r&3)+8*(r>>2)+4*l1, col=l31
  #pragma unroll
  for (int mi = 0; mi < 2; ++mi) {
    #pragma unroll
    for (int ni = 0; ni < 4; ++ni) {
      #pragma unroll
      for (int r = 0; r < 16; ++r) {
        const int grow = row0 + wr + mi * 32 + (r & 3) + 8 * (r >> 2) + 4 * l1;
        const int gcol = col0 + ni * 32 + l31;
        Cf[(size_t)kz * 8388608 + ((size_t)grow << 10) + gcol] = acc[mi][ni][r];
      }
    }
  }
}

// ---------------- GEMM A: 256x128 tile, BK=64, triple-buffer 144KB ----------------
template<int MODE>
__global__ __launch_bounds__(512, 2)
void gemm3_k(const u16* __restrict__ A, const u16* __restrict__ B,
             u16* __restrict__ Cb, float* __restrict__ Cf,
             const float* __restrict__ bias, const float* __restrict__ resid,
             int Ktot, int ntn_sh) {
  __shared__ u16 lds[3 * 24576];
  const int tid = threadIdx.x;
  const int lane = tid & 63;
  const int w = tid >> 6;
  const int l15 = lane & 15, l4 = lane >> 4;

  const int nwg = gridDim.x;
  const int bid = blockIdx.x;
  const int lb = (bid & 7) * (nwg >> 3) + (bid >> 3);
  const int tm = lb >> ntn_sh;
  const int tn = lb & ((1 << ntn_sh) - 1);
  const int row0 = tm * 256, col0 = tn * 128;
  const int wr = (w >> 1) * 64, wc = (w & 1) * 64;

  const int sr = w * 8 + (lane >> 3);
  const int pp = (lane & 7) ^ (lane >> 3);

  f32x4 acc[4][4];
  #pragma unroll
  for (int i = 0; i < 4; ++i)
    #pragma unroll
    for (int jj = 0; jj < 4; ++jj)
      acc[i][jj] = (f32x4){0.f, 0.f, 0.f, 0.f};

  const int nK = Ktot >> 6;

  auto stage = [&](int kt, u16* buf) {
    u16* da = buf + (size_t)w * 512;
    u16* db = buf + 16384 + (size_t)w * 512;
    const int k0 = kt << 6;
    #pragma unroll
    for (int u = 0; u < 4; ++u) {
      const u16* ga = A + (size_t)(row0 + u * 64 + sr) * Ktot + k0 + pp * 8;
      gload16(ga, da + u * 4096);
    }
    #pragma unroll
    for (int u = 0; u < 2; ++u) {
      const u16* gb = B + (size_t)(col0 + u * 64 + sr) * Ktot + k0 + pp * 8;
      gload16(gb, db + u * 4096);
    }
  };

  auto compute = [&](const u16* buf) {
    const char* Ar = (const char*)buf;
    const char* Br = (const char*)(buf + 16384);
    #pragma unroll
    for (int ks = 0; ks < 2; ++ks) {
      const int bcol = ((ks << 6) + (l4 << 4)) ^ ((l15 & 7) << 4);
      short8 av[4], bv[4];
      #pragma unroll
      for (int mi = 0; mi < 4; ++mi)
        av[mi] = *(const short8*)(Ar + (wr + mi * 16 + l15) * 128 + bcol);
      #pragma unroll
      for (int ni = 0; ni < 4; ++ni)
        bv[ni] = *(const short8*)(Br + (wc + ni * 16 + l15) * 128 + bcol);
      __builtin_amdgcn_s_setprio(1);
      #pragma unroll
      for (int mi = 0; mi < 4; ++mi)
        #pragma unroll
        for (int ni = 0; ni < 4; ++ni)
          acc[mi][ni] = __builtin_amdgcn_mfma_f32_16x16x32_bf16(av[mi], bv[ni], acc[mi][ni], 0, 0, 0);
      __builtin_amdgcn_s_setprio(0);
    }
  };

  u16* pb0 = lds;
  u16* pb1 = lds + 24576;
  u16* pb2 = lds + 49152;

  stage(0, pb0);
  stage(1, pb1);
  for (int t = 0; t < nK; ++t) {
    if (t + 1 < nK) {
      asm volatile("s_waitcnt vmcnt(6)" ::: "memory");
    } else {
      asm volatile("s_waitcnt vmcnt(0)" ::: "memory");
    }
    __builtin_amdgcn_s_barrier();
    if (t + 2 < nK) stage(t + 2, pb2);
    compute(pb0);
    u16* tmp = pb0; pb0 = pb1; pb1 = pb2; pb2 = tmp;
  }

  #pragma unroll
  for (int mi = 0; mi < 4; ++mi) {
    #pragma unroll
    for (int ni = 0; ni < 4; ++ni) {
      #pragma unroll
      for (int j = 0; j < 4; ++j) {
        const int grow = row0 + wr + mi * 16 + l4 * 4 + j;
        const int gcol = col0 + wc + ni * 16 + l15;
        const float v = acc[mi][ni][j];
        if constexpr (MODE == GM_PLAIN) {
          Cb[((size_t)grow << 10) + gcol] = f2bf(v);
        } else if constexpr (MODE == GM_PROJ) {
          const size_t o = ((size_t)grow << 10) + gcol;
          Cf[o] = v + bias[gcol] + resid[o];
        }
      }
    }
  }
}

// ---------------- GEMM B: 256x128 tile, BK=32, 8 waves, 72KB -> 2 blocks/CU ----------------
template<int MODE>
__global__ __launch_bounds__(512, 4)
void gemm5_k(const u16* __restrict__ A, const u16* __restrict__ B,
             u16* __restrict__ Cb, u16* __restrict__ Cb2,
             int Ktot, int ntn_sh) {
  __shared__ u16 lds[3 * 12288];
  const int tid = threadIdx.x;
  const int lane = tid & 63;
  const int w = tid >> 6;
  const int l15 = lane & 15, l4 = lane >> 4;

  const int nwg = gridDim.x;
  const int bid = blockIdx.x;
  const int lb = (bid & 7) * (nwg >> 3) + (bid >> 3);
  const int tm = lb >> ntn_sh;
  const int tn = lb & ((1 << ntn_sh) - 1);
  const int row0 = tm * 256, col0 = tn * 128;
  const int wr = (w >> 1) * 64, wc = (w & 1) * 64;

  const int str = tid >> 2;
  const int sgc = tid & 3;

  f32x4 acc[4][4];
  #pragma unroll
  for (int i = 0; i < 4; ++i)
    #pragma unroll
    for (int jj = 0; jj < 4; ++jj)
      acc[i][jj] = (f32x4){0.f, 0.f, 0.f, 0.f};

  const int nKt = Ktot >> 5;

  auto stage = [&](int kt, u16* buf) {
    const int k0 = kt << 5;
    #pragma unroll
    for (int u = 0; u < 2; ++u) {
      const int r = u * 128 + str;
      const int swz = sgc ^ ((r >> 1) & 3);
      const u16* ga = A + (size_t)(row0 + r) * Ktot + k0 + swz * 8;
      gload16(ga, buf + ((size_t)u * 512 + tid) * 8);
    }
    {
      const int swz = sgc ^ ((str >> 1) & 3);
      const u16* gb = B + (size_t)(col0 + str) * Ktot + k0 + swz * 8;
      gload16(gb, buf + 8192 + (size_t)tid * 8);
    }
  };

  auto compute = [&](const u16* buf) {
    short8 av[4], bv[4];
    #pragma unroll
    for (int mi = 0; mi < 4; ++mi) {
      const int row = wr + mi * 16 + l15;
      const int g = l4 ^ ((row >> 1) & 3);
      av[mi] = *(const short8*)(buf + row * 32 + g * 8);
    }
    #pragma unroll
    for (int ni = 0; ni < 4; ++ni) {
      const int row = wc + ni * 16 + l15;
      const int g = l4 ^ ((row >> 1) & 3);
      bv[ni] = *(const short8*)(buf + 8192 + row * 32 + g * 8);
    }
    __builtin_amdgcn_s_setprio(1);
    #pragma unroll
    for (int mi = 0; mi < 4; ++mi)
      #pragma unroll
      for (int ni = 0; ni < 4; ++ni)
        acc[mi][ni] = __builtin_amdgcn_mfma_f32_16x16x32_bf16(av[mi], bv[ni], acc[mi][ni], 0, 0, 0);
    __builtin_amdgcn_s_setprio(0);
  };

  u16* pb0 = lds;
  u16* pb1 = lds + 12288;
  u16* pb2 = lds + 24576;

  stage(0, pb0);
  stage(1, pb1);
  for (int t = 0; t < nKt; ++t) {
    if (t + 1 < nKt) {
      asm volatile("s_waitcnt vmcnt(3)" ::: "memory");
    } else {
      asm volatile("s_waitcnt vmcnt(0)" ::: "memory");
    }
    __builtin_amdgcn_s_barrier();
    if (t + 2 < nKt) stage(t + 2, pb2);
    compute(pb0);
    u16* tmp = pb0; pb0 = pb1; pb1 = pb2; pb2 = tmp;
  }

  #pragma unroll
  for (int mi = 0; mi < 4; ++mi) {
    #pragma unroll
    for (int ni = 0; ni < 4; ++ni) {
      #pragma unroll
      for (int j = 0; j < 4; ++j) {
        const int grow = row0 + wr + mi * 16 + l4 * 4 + j;
        const int gcol = col0 + wc + ni * 16 + l15;
        const float v = acc[mi][ni][j];
        if constexpr (MODE == GM_KV) {
          if (gcol < 1024) {
            Cb[((size_t)grow << 10) + gcol] = f2bf(v);
          } else {
            const int c = gcol - 1024;
            const int b = grow >> 10, ms = grow & 1023;
            const int h = c >> 7, d = c & 127;
            Cb2[((size_t)((b * 8 + h) * 128 + d) << 10) + ms] = f2bf(v);
          }
        }
      }
    }
  }
}

// ---------------- flash attention (double-buffered, KV-locality XCD remap) ----------------
__global__ __launch_bounds__(256, 2)
void attn2_k(const u16* __restrict__ Q, const u16* __restrict__ K,
             const u16* __restrict__ Vt, u16* __restrict__ O) {
  __shared__ u16 Ks[2][64 * 128];
  __shared__ u16 Vs[2][128 * 64];
  __shared__ u16 Plds[4][16 * 80];
  // chunked remap: each XCD gets 8 contiguous heads (4MB KV = one L2) x all mtiles
  const int bid = blockIdx.x;                 // grid = 1024
  const int lb = (bid & 7) * 128 + (bid >> 3);
  const int bh = lb >> 4;
  const int mtile = lb & 15;
  const int b = bh >> 3, h = bh & 7;
  const int tid = threadIdx.x, lane = tid & 63, w = tid >> 6;
  const int l15 = lane & 15, l4 = lane >> 4;

  short8 qf[4];
  {
    const int qrow = b * 1024 + mtile * 64 + w * 16 + l15;
    const u16* qb = Q + ((size_t)qrow << 10) + h * 128;
    #pragma unroll
    for (int kk = 0; kk < 4; ++kk)
      qf[kk] = *(const short8*)(qb + kk * 32 + l4 * 8);
  }

  f32x4 o[8];
  #pragma unroll
  for (int db = 0; db < 8; ++db) o[db] = (f32x4){0.f, 0.f, 0.f, 0.f};
  float mrow[4], lrow[4];
  #pragma unroll
  for (int j = 0; j < 4; ++j) { mrow[j] = -1e30f; lrow[j] = 0.f; }
  const float scale = 0.08838834764831845f;

  auto stageKV = [&](int kt, int half) {
    #pragma unroll
    for (int j = 0; j < 4; ++j) {
      const int c = (j * 4 + w) * 64 + lane;
      const int r = c >> 4;
      const int coff = (((c & 15) ^ (r & 7)) << 3);
      const u16* gp = K + ((size_t)(b * 1024 + kt * 64 + r) << 10) + h * 128 + coff;
      gload16(gp, (void*)(Ks[half] + (j * 4 + w) * 512));
    }
    #pragma unroll
    for (int j = 0; j < 4; ++j) {
      const int c = (j * 4 + w) * 64 + lane;
      const int r = c >> 3;
      const int coff = (((c & 7) ^ (r & 7)) << 3);
      const u16* gp = Vt + ((size_t)((b * 8 + h) * 128 + r) << 10) + kt * 64 + coff;
      gload16(gp, (void*)(Vs[half] + (j * 4 + w) * 512));
    }
  };

  stageKV(0, 0);
  for (int kt = 0; kt < 16; ++kt) {
    const int cur = kt & 1;
    asm volatile("s_waitcnt vmcnt(0)" ::: "memory");
    __builtin_amdgcn_s_barrier();
    if (kt + 1 < 16) stageKV(kt + 1, cur ^ 1);

    const u16* ks_ = Ks[cur];
    const u16* vs_ = Vs[cur];
    f32x4 s[4];
    #pragma unroll
    for (int cb = 0; cb < 4; ++cb) {
      s[cb] = (f32x4){0.f, 0.f, 0.f, 0.f};
      #pragma unroll
      for (int kk = 0; kk < 4; ++kk) {
        const int col = (kk * 32 + l4 * 8) ^ ((l15 & 7) << 3);
        short8 bK = *(const short8*)(ks_ + (cb * 16 + l15) * 128 + col);
        s[cb] = __builtin_amdgcn_mfma_f32_16x16x32_bf16(qf[kk], bK, s[cb], 0, 0, 0);
      }
    }
    #pragma unroll
    for (int cb = 0; cb < 4; ++cb) {
      s[cb][0] *= scale; s[cb][1] *= scale; s[cb][2] *= scale; s[cb][3] *= scale;
    }
    #pragma unroll
    for (int j = 0; j < 4; ++j) {
      float mx = fmaxf(fmaxf(s[0][j], s[1][j]), fmaxf(s[2][j], s[3][j]));
      #pragma unroll
      for (int off = 8; off >= 1; off >>= 1)
        mx = fmaxf(mx, __shfl_xor(mx, off, 64));
      const float mn = fmaxf(mrow[j], mx);
      const float fac = __expf(mrow[j] - mn);
      mrow[j] = mn;
      float rs = 0.f;
      #pragma unroll
      for (int cb = 0; cb < 4; ++cb) {
        const float p = __expf(s[cb][j] - mn);
        s[cb][j] = p;
        rs += p;
      }
      #pragma unroll
      for (int off = 8; off >= 1; off >>= 1)
        rs += __shfl_xor(rs, off, 64);
      lrow[j] = lrow[j] * fac + rs;
      #pragma unroll
      for (int db = 0; db < 8; ++db) o[db][j] *= fac;
    }
    u16* pl = Plds[w];
    #pragma unroll
    for (int cb = 0; cb < 4; ++cb)
      #pragma unroll
      for (int j = 0; j < 4; ++j)
        pl[(l4 * 4 + j) * 80 + cb * 16 + l15] = f2bf(s[cb][j]);
    asm volatile("s_waitcnt lgkmcnt(0)" ::: "memory");
    __builtin_amdgcn_sched_barrier(0);
    short8 ap[2];
    #pragma unroll
    for (int ks2 = 0; ks2 < 2; ++ks2)
      ap[ks2] = *(const short8*)(pl + l15 * 80 + ks2 * 32 + l4 * 8);
    #pragma unroll
    for (int db = 0; db < 8; ++db) {
      #pragma unroll
      for (int ks2 = 0; ks2 < 2; ++ks2) {
        const int col = (ks2 * 32 + l4 * 8) ^ ((l15 & 7) << 3);
        short8 bV = *(const short8*)(vs_ + (db * 16 + l15) * 64 + col);
        o[db] = __builtin_amdgcn_mfma_f32_16x16x32_bf16(ap[ks2], bV, o[db], 0, 0, 0);
      }
    }
  }
  #pragma unroll
  for (int db = 0; db < 8; ++db) {
    #pragma unroll
    for (int j = 0; j < 4; ++j) {
      const int grow = b * 1024 + mtile * 64 + w * 16 + l4 * 4 + j;
      const int gcol = h * 128 + db * 16 + l15;
      O[((size_t)grow << 10) + gcol] = f2bf(o[db][j] / lrow[j]);
    }
  }
}

// ---------------- launch ----------------

extern "C" void kernel_launch(void* const* d_in, const int* in_sizes, int n_in,
                              void* d_out, int out_size, void* d_ws, size_t ws_size,
                              hipStream_t stream) {
  const float* x1     = (const float*)d_in[0];
  const float* x2     = (const float*)d_in[1];
  const float* conv_w = (const float*)d_in[2];
  const float* conv_b = (const float*)d_in[3];
  const float* wq     = (const float*)d_in[4];
  const float* wk     = (const float*)d_in[5];
  const float* wv     = (const float*)d_in[6];
  const float* proj_w = (const float*)d_in[7];
  const float* proj_b = (const float*)d_in[8];
  float* out = (float*)d_out;

  char* ws = (char*)d_ws;
  size_t off = 0;
  auto alloc = [&](size_t bytes) -> void* {
    void* p = ws + off;
    off += (bytes + 255) & ~(size_t)255;
    return p;
  };
  u16* x1b  = (u16*)alloc(8192ULL * 1024 * 2);
  u16* in_t_pad = (u16*)alloc((9248ULL + 96) * 2048 * 2);
  const size_t pad_bytes = 9248ULL * 2048 * 2;
  u16* Wp   = (u16*)alloc(9ULL * 2097152 * 2);
  u16* wqb  = (u16*)alloc(1048576ULL * 2);
  u16* wkb  = (u16*)alloc(1048576ULL * 2);
  u16* wvb  = (u16*)alloc(1048576ULL * 2);
  u16* pjb  = (u16*)alloc(1048576ULL * 2);
  u16* xc   = (u16*)alloc(8192ULL * 1024 * 2);
  u16* Qb   = (u16*)alloc(8192ULL * 1024 * 2);
  u16* Kb   = (u16*)alloc(8192ULL * 1024 * 2);
  u16* Vtb  = (u16*)alloc(8192ULL * 1024 * 2);
  u16* Ob   = (u16*)alloc(8192ULL * 1024 * 2);
  float* pConv = (float*)Qb;   // split-K f32 partials alias Qb..Ob

  // prep
  (void)hipMemsetAsync(in_t_pad, 0, pad_bytes + 96ULL * 2048 * 2, stream);
  cast4_k<<<dim3(1024, 4), 256, 0, stream>>>(wq, wk, wv, proj_w, wqb, wkb, wvb, pjb);
  build_pad<<<dim3(32, 16, 8), 256, 0, stream>>>(x1, x2, in_t_pad, x1b);
  pack_wp<<<8192, 256, 0, stream>>>(conv_w, Wp);

  // conv: halo-reuse implicit GEMM, 32x32x16 MFMA, split-K x2
  conv8_k<<<512, 256, 0, stream>>>(in_t_pad, Wp, pConv);
  addc_k<<<dim3(16, 16, 8), 256, 0, stream>>>(pConv, conv_b, xc);
  // Q
  gemm3_k<GM_PLAIN><<<256, 512, 0, stream>>>(x1b, wqb, Qb, nullptr, nullptr, nullptr, 1024, 3);
  // fused K+V
  gemm5_k<GM_KV><<<512, 512, 0, stream>>>(xc, wkb, Kb, Vtb, 1024, 4);
  // attention (1D grid, KV-locality remap)
  attn2_k<<<1024, 256, 0, stream>>>(Qb, Kb, Vtb, Ob);
  // projection + bias + residual
  gemm3_k<GM_PROJ><<<256, 512, 0, stream>>>(Ob, pjb, nullptr, out, proj_b, x1, 1024, 3);
}

// Round 10
// 519.805 us; speedup vs baseline: 1.1625x; 1.0688x over previous
//
#include <hip/hip_runtime.h>
#include <hip/hip_bf16.h>
#include <cstdint>
#include <cstddef>

typedef __attribute__((ext_vector_type(8))) short short8;
typedef __attribute__((ext_vector_type(4))) float f32x4;
typedef unsigned short u16;

static __device__ __forceinline__ u16 f2bf(float f) {
  __hip_bfloat16 h = __float2bfloat16(f);
  return *reinterpret_cast<u16*>(&h);
}

static __device__ __forceinline__ void gload16(const void* g, void* l) {
  __builtin_amdgcn_global_load_lds(
      (const __attribute__((address_space(1))) void*)g,
      (__attribute__((address_space(3))) void*)l, 16, 0, 0);
}

// ---------------- prep kernels ----------------

__global__ void cast4_k(const float* __restrict__ a, const float* __restrict__ b,
                        const float* __restrict__ c, const float* __restrict__ d,
                        u16* __restrict__ oa, u16* __restrict__ ob,
                        u16* __restrict__ oc, u16* __restrict__ od) {
  const int which = blockIdx.y;
  const float* src = (which == 0) ? a : (which == 1) ? b : (which == 2) ? c : d;
  u16* dst = (which == 0) ? oa : (which == 1) ? ob : (which == 2) ? oc : od;
  int i = blockIdx.x * 256 + threadIdx.x;
  float4 v = ((const float4*)src)[i];
  union { u16 u[4]; uint2 p; } r;
  r.u[0] = f2bf(v.x); r.u[1] = f2bf(v.y); r.u[2] = f2bf(v.z); r.u[3] = f2bf(v.w);
  ((uint2*)dst)[i] = r.p;
}

// in_t_pad[(b*34 + y+1)*34 + x+1][i] = bf16( concat(x1,x2)[b][i][y*32+x] )
__global__ void build_pad(const float* __restrict__ x1, const float* __restrict__ x2,
                          u16* __restrict__ in_t_pad, u16* __restrict__ x1b) {
  __shared__ float tile[64][65];
  const int it = blockIdx.x;
  const int st = blockIdx.y;
  const int b  = blockIdx.z;
  const int i0 = it * 64, s0 = st * 64;
  const bool isx1 = (i0 < 1024);
  const float* src = isx1
      ? x1 + ((size_t)b * 1024 + i0) * 1024
      : x2 + ((size_t)b * 1024 + (i0 - 1024)) * 1024;
  const int t = threadIdx.x;
  #pragma unroll
  for (int jj = 0; jj < 16; ++jj) {
    int idx = jj * 256 + t;
    int ii = idx >> 6, si = idx & 63;
    float v = src[(size_t)ii * 1024 + s0 + si];
    tile[ii][si] = v;
    if (isx1)
      x1b[((size_t)b * 1024 + i0 + ii) * 1024 + s0 + si] = f2bf(v);
  }
  __syncthreads();
  #pragma unroll
  for (int jj = 0; jj < 16; ++jj) {
    int idx = jj * 256 + t;
    int si = idx >> 6, ii = idx & 63;
    const int s = s0 + si;
    const int prow = (b * 34 + (s >> 5) + 1) * 34 + (s & 31) + 1;
    in_t_pad[(size_t)prow * 2048 + i0 + ii] = f2bf(tile[ii][si]);
  }
}

// Wp[q][o][i] = bf16( conv_w[o][i][q] ),  q = ky*3+kx
__global__ void pack_wp(const float* __restrict__ cw, u16* __restrict__ Wp) {
  __shared__ float sb[2304];
  const int blk = blockIdx.x;
  const int t = threadIdx.x;
  const size_t base = (size_t)blk * 2304;
  #pragma unroll
  for (int jj = 0; jj < 9; ++jj) sb[jj * 256 + t] = cw[base + jj * 256 + t];
  __syncthreads();
  const int p = blk * 256 + t;
  #pragma unroll
  for (int q = 0; q < 9; ++q)
    Wp[(size_t)q * 2097152 + p] = f2bf(sb[t * 9 + q]);
}

// split-K combine: xc[b][o][s] = bf16(p0 + p1 + bias[o]); p is [kz][b*1024+s][o] f32
__global__ void addc_k(const float* __restrict__ p, const float* __restrict__ bias,
                       u16* __restrict__ xc) {
  __shared__ float tile[64][65];
  const int st = blockIdx.x;
  const int ot = blockIdx.y;
  const int b  = blockIdx.z;
  const int s0 = st * 64, o0 = ot * 64;
  const int t = threadIdx.x;
  const float* p1 = p + 8388608;
  #pragma unroll
  for (int jj = 0; jj < 16; ++jj) {
    int idx = jj * 256 + t;
    int si = idx >> 6, oi = idx & 63;
    const size_t m = ((size_t)b * 1024 + s0 + si) * 1024 + o0 + oi;
    tile[si][oi] = p[m] + p1[m] + bias[o0 + oi];
  }
  __syncthreads();
  #pragma unroll
  for (int jj = 0; jj < 16; ++jj) {
    int idx = jj * 256 + t;
    int oi = idx >> 6, si = idx & 63;
    xc[((size_t)b * 1024 + o0 + oi) * 1024 + s0 + si] = f2bf(tile[si][oi]);
  }
}

enum { GM_PLAIN = 0, GM_PROJ = 2, GM_KV = 4 };

// ---------------- conv GEMM: halo reuse, 256x256 block, 4 waves, wave tile 128x128
// 8x8 frags of 16x16x32 -> 16 LDS frag-reads per 64 MFMA (perimeter ratio 0.25,
// 3x less LDS-read traffic per FLOP than the 64x128 wave tile). 1 wave/SIMD;
// ILP from 64 independent accs. Halo dbuf (2x24KB) + B 3-buf (3x16KB) = 96KB.
__global__ __launch_bounds__(256, 1)
void conv9_k(const u16* __restrict__ Ap, const u16* __restrict__ B,
             float* __restrict__ Cf) {
  __shared__ u16 lds[2 * 12288 + 3 * 8192];
  const int tid = threadIdx.x;
  const int lane = tid & 63, w = tid >> 6;
  const int l15 = lane & 15, l4 = lane >> 4;

  // T1 XCD remap, grid 256 (2 kz x 128 tiles)
  const int bid = blockIdx.x;
  const int lb = (bid & 7) * 32 + (bid >> 3);
  const int kz = lb >> 7;
  const int tile = lb & 127;
  const int tm = tile >> 2, tn = tile & 3;
  const int row0 = tm * 256, col0 = tn * 256;
  const int b = tm >> 2;
  const int y0 = (tm & 3) * 8;
  const int hb = (b * 34 + y0) * 34;       // halo base pad-row
  const int wr = (w >> 1) * 128, wc = (w & 1) * 128;
  const int chbase = kz * 1024;

  // per-thread A-frag pad-row offsets (8 mi row-blocks of 16)
  int pr[8];
  #pragma unroll
  for (int mi = 0; mi < 8; ++mi) {
    const int m = row0 + wr + mi * 16 + l15;
    const int y = (m >> 5) & 31, x = m & 31;
    pr[mi] = (y - y0 + 1) * 34 + x + 1;    // +dd stays in [0,340)
  }

  const int srow = tid >> 2;   // 0..63
  const int sgc = tid & 3;

  f32x4 acc[8][8];
  #pragma unroll
  for (int i = 0; i < 8; ++i)
    #pragma unroll
    for (int jj = 0; jj < 8; ++jj)
      acc[i][jj] = (f32x4){0.f, 0.f, 0.f, 0.f};

  auto stageHalo = [&](int cc, int half) {   // 6 loads/thread
    u16* dst = lds + half * 12288;
    #pragma unroll
    for (int rnd = 0; rnd < 6; ++rnd) {
      const int row = rnd * 64 + srow;       // 0..383
      const int g = sgc ^ ((row >> 1) & 3);
      const u16* src = Ap + (size_t)(hb + row) * 2048 + chbase + cc * 32 + g * 8;
      gload16(src, dst + (size_t)(rnd * 256 + tid) * 8);
    }
  };
  auto stageB = [&](int cc, int q) {         // 4 loads/thread (256 rows)
    u16* dst = lds + 24576 + (q % 3) * 8192;
    #pragma unroll
    for (int rnd = 0; rnd < 4; ++rnd) {
      const int r = rnd * 64 + srow;         // 0..255
      const int g = sgc ^ ((r >> 1) & 3);
      const u16* src = B + ((size_t)q << 21) + (size_t)(col0 + r) * 2048
                       + chbase + cc * 32 + g * 8;
      gload16(src, dst + (size_t)(rnd * 256 + tid) * 8);
    }
  };

  constexpr int ddt[9] = {-35, -34, -33, -1, 0, 1, 33, 34, 35};
  constexpr int NC = 32;

  // prologue
  stageHalo(0, 0);
  stageHalo(1, 1);
  stageB(0, 0);
  stageB(0, 1);

  for (int cc = 0; cc < NC; ++cc) {
    const u16* hcur = lds + (cc & 1) * 12288;
    const bool interior = (cc >= 1 && cc <= NC - 2);
    #pragma unroll
    for (int q = 0; q < 9; ++q) {
      // ---- wait + barrier ----
      if ((q == 1 || q == 2) && interior) {
        asm volatile("s_waitcnt vmcnt(10)" ::: "memory");
      } else if (q == 8 && cc == NC - 1) {
        asm volatile("s_waitcnt vmcnt(0)" ::: "memory");
      } else {
        asm volatile("s_waitcnt vmcnt(4)" ::: "memory");
      }
      __builtin_amdgcn_s_barrier();
      // ---- stage ----
      {
        const int gp2 = cc * 9 + q + 2;
        if (gp2 <= NC * 9 - 1) {
          int qS = q + 2, ccS = cc;
          if (qS >= 9) { qS -= 9; ccS += 1; }
          stageB(ccS, qS);
        }
        if (q == 0 && cc >= 1 && cc <= NC - 2)
          stageHalo(cc + 1, (cc + 1) & 1);
      }
      // ---- compute plane q (one K=32 step, 8x8 frags) ----
      {
        const u16* bq = lds + 24576 + (q % 3) * 8192;
        const int dd = ddt[q];
        short8 av[8], bv[8];
        #pragma unroll
        for (int mi = 0; mi < 8; ++mi) {
          const int hr = pr[mi] + dd;
          const int g = l4 ^ ((hr >> 1) & 3);
          av[mi] = *(const short8*)(hcur + hr * 32 + g * 8);
        }
        #pragma unroll
        for (int ni = 0; ni < 8; ++ni) {
          const int r = wc + ni * 16 + l15;
          const int g = l4 ^ ((r >> 1) & 3);
          bv[ni] = *(const short8*)(bq + r * 32 + g * 8);
        }
        __builtin_amdgcn_s_setprio(1);
        #pragma unroll
        for (int mi = 0; mi < 8; ++mi)
          #pragma unroll
          for (int ni = 0; ni < 8; ++ni)
            acc[mi][ni] = __builtin_amdgcn_mfma_f32_16x16x32_bf16(av[mi], bv[ni], acc[mi][ni], 0, 0, 0);
        __builtin_amdgcn_s_setprio(0);
      }
    }
  }

  // epilogue: f32 partials [kz][m][o]
  #pragma unroll
  for (int mi = 0; mi < 8; ++mi) {
    #pragma unroll
    for (int ni = 0; ni < 8; ++ni) {
      #pragma unroll
      for (int j = 0; j < 4; ++j) {
        const int grow = row0 + wr + mi * 16 + l4 * 4 + j;
        const int gcol = col0 + wc + ni * 16 + l15;
        Cf[(size_t)kz * 8388608 + ((size_t)grow << 10) + gcol] = acc[mi][ni][j];
      }
    }
  }
}

// ---------------- GEMM A: 256x128 tile, BK=64, triple-buffer 144KB ----------------
template<int MODE>
__global__ __launch_bounds__(512, 2)
void gemm3_k(const u16* __restrict__ A, const u16* __restrict__ B,
             u16* __restrict__ Cb, float* __restrict__ Cf,
             const float* __restrict__ bias, const float* __restrict__ resid,
             int Ktot, int ntn_sh) {
  __shared__ u16 lds[3 * 24576];
  const int tid = threadIdx.x;
  const int lane = tid & 63;
  const int w = tid >> 6;
  const int l15 = lane & 15, l4 = lane >> 4;

  const int nwg = gridDim.x;
  const int bid = blockIdx.x;
  const int lb = (bid & 7) * (nwg >> 3) + (bid >> 3);
  const int tm = lb >> ntn_sh;
  const int tn = lb & ((1 << ntn_sh) - 1);
  const int row0 = tm * 256, col0 = tn * 128;
  const int wr = (w >> 1) * 64, wc = (w & 1) * 64;

  const int sr = w * 8 + (lane >> 3);
  const int pp = (lane & 7) ^ (lane >> 3);

  f32x4 acc[4][4];
  #pragma unroll
  for (int i = 0; i < 4; ++i)
    #pragma unroll
    for (int jj = 0; jj < 4; ++jj)
      acc[i][jj] = (f32x4){0.f, 0.f, 0.f, 0.f};

  const int nK = Ktot >> 6;

  auto stage = [&](int kt, u16* buf) {
    u16* da = buf + (size_t)w * 512;
    u16* db = buf + 16384 + (size_t)w * 512;
    const int k0 = kt << 6;
    #pragma unroll
    for (int u = 0; u < 4; ++u) {
      const u16* ga = A + (size_t)(row0 + u * 64 + sr) * Ktot + k0 + pp * 8;
      gload16(ga, da + u * 4096);
    }
    #pragma unroll
    for (int u = 0; u < 2; ++u) {
      const u16* gb = B + (size_t)(col0 + u * 64 + sr) * Ktot + k0 + pp * 8;
      gload16(gb, db + u * 4096);
    }
  };

  auto compute = [&](const u16* buf) {
    const char* Ar = (const char*)buf;
    const char* Br = (const char*)(buf + 16384);
    #pragma unroll
    for (int ks = 0; ks < 2; ++ks) {
      const int bcol = ((ks << 6) + (l4 << 4)) ^ ((l15 & 7) << 4);
      short8 av[4], bv[4];
      #pragma unroll
      for (int mi = 0; mi < 4; ++mi)
        av[mi] = *(const short8*)(Ar + (wr + mi * 16 + l15) * 128 + bcol);
      #pragma unroll
      for (int ni = 0; ni < 4; ++ni)
        bv[ni] = *(const short8*)(Br + (wc + ni * 16 + l15) * 128 + bcol);
      __builtin_amdgcn_s_setprio(1);
      #pragma unroll
      for (int mi = 0; mi < 4; ++mi)
        #pragma unroll
        for (int ni = 0; ni < 4; ++ni)
          acc[mi][ni] = __builtin_amdgcn_mfma_f32_16x16x32_bf16(av[mi], bv[ni], acc[mi][ni], 0, 0, 0);
      __builtin_amdgcn_s_setprio(0);
    }
  };

  u16* pb0 = lds;
  u16* pb1 = lds + 24576;
  u16* pb2 = lds + 49152;

  stage(0, pb0);
  stage(1, pb1);
  for (int t = 0; t < nK; ++t) {
    if (t + 1 < nK) {
      asm volatile("s_waitcnt vmcnt(6)" ::: "memory");
    } else {
      asm volatile("s_waitcnt vmcnt(0)" ::: "memory");
    }
    __builtin_amdgcn_s_barrier();
    if (t + 2 < nK) stage(t + 2, pb2);
    compute(pb0);
    u16* tmp = pb0; pb0 = pb1; pb1 = pb2; pb2 = tmp;
  }

  #pragma unroll
  for (int mi = 0; mi < 4; ++mi) {
    #pragma unroll
    for (int ni = 0; ni < 4; ++ni) {
      #pragma unroll
      for (int j = 0; j < 4; ++j) {
        const int grow = row0 + wr + mi * 16 + l4 * 4 + j;
        const int gcol = col0 + wc + ni * 16 + l15;
        const float v = acc[mi][ni][j];
        if constexpr (MODE == GM_PLAIN) {
          Cb[((size_t)grow << 10) + gcol] = f2bf(v);
        } else if constexpr (MODE == GM_PROJ) {
          const size_t o = ((size_t)grow << 10) + gcol;
          Cf[o] = v + bias[gcol] + resid[o];
        }
      }
    }
  }
}

// ---------------- GEMM B: 256x128 tile, BK=32, 8 waves, 72KB -> 2 blocks/CU ----------------
template<int MODE>
__global__ __launch_bounds__(512, 4)
void gemm5_k(const u16* __restrict__ A, const u16* __restrict__ B,
             u16* __restrict__ Cb, u16* __restrict__ Cb2,
             int Ktot, int ntn_sh) {
  __shared__ u16 lds[3 * 12288];
  const int tid = threadIdx.x;
  const int lane = tid & 63;
  const int w = tid >> 6;
  const int l15 = lane & 15, l4 = lane >> 4;

  const int nwg = gridDim.x;
  const int bid = blockIdx.x;
  const int lb = (bid & 7) * (nwg >> 3) + (bid >> 3);
  const int tm = lb >> ntn_sh;
  const int tn = lb & ((1 << ntn_sh) - 1);
  const int row0 = tm * 256, col0 = tn * 128;
  const int wr = (w >> 1) * 64, wc = (w & 1) * 64;

  const int str = tid >> 2;
  const int sgc = tid & 3;

  f32x4 acc[4][4];
  #pragma unroll
  for (int i = 0; i < 4; ++i)
    #pragma unroll
    for (int jj = 0; jj < 4; ++jj)
      acc[i][jj] = (f32x4){0.f, 0.f, 0.f, 0.f};

  const int nKt = Ktot >> 5;

  auto stage = [&](int kt, u16* buf) {
    const int k0 = kt << 5;
    #pragma unroll
    for (int u = 0; u < 2; ++u) {
      const int r = u * 128 + str;
      const int swz = sgc ^ ((r >> 1) & 3);
      const u16* ga = A + (size_t)(row0 + r) * Ktot + k0 + swz * 8;
      gload16(ga, buf + ((size_t)u * 512 + tid) * 8);
    }
    {
      const int swz = sgc ^ ((str >> 1) & 3);
      const u16* gb = B + (size_t)(col0 + str) * Ktot + k0 + swz * 8;
      gload16(gb, buf + 8192 + (size_t)tid * 8);
    }
  };

  auto compute = [&](const u16* buf) {
    short8 av[4], bv[4];
    #pragma unroll
    for (int mi = 0; mi < 4; ++mi) {
      const int row = wr + mi * 16 + l15;
      const int g = l4 ^ ((row >> 1) & 3);
      av[mi] = *(const short8*)(buf + row * 32 + g * 8);
    }
    #pragma unroll
    for (int ni = 0; ni < 4; ++ni) {
      const int row = wc + ni * 16 + l15;
      const int g = l4 ^ ((row >> 1) & 3);
      bv[ni] = *(const short8*)(buf + 8192 + row * 32 + g * 8);
    }
    __builtin_amdgcn_s_setprio(1);
    #pragma unroll
    for (int mi = 0; mi < 4; ++mi)
      #pragma unroll
      for (int ni = 0; ni < 4; ++ni)
        acc[mi][ni] = __builtin_amdgcn_mfma_f32_16x16x32_bf16(av[mi], bv[ni], acc[mi][ni], 0, 0, 0);
    __builtin_amdgcn_s_setprio(0);
  };

  u16* pb0 = lds;
  u16* pb1 = lds + 12288;
  u16* pb2 = lds + 24576;

  stage(0, pb0);
  stage(1, pb1);
  for (int t = 0; t < nKt; ++t) {
    if (t + 1 < nKt) {
      asm volatile("s_waitcnt vmcnt(3)" ::: "memory");
    } else {
      asm volatile("s_waitcnt vmcnt(0)" ::: "memory");
    }
    __builtin_amdgcn_s_barrier();
    if (t + 2 < nKt) stage(t + 2, pb2);
    compute(pb0);
    u16* tmp = pb0; pb0 = pb1; pb1 = pb2; pb2 = tmp;
  }

  #pragma unroll
  for (int mi = 0; mi < 4; ++mi) {
    #pragma unroll
    for (int ni = 0; ni < 4; ++ni) {
      #pragma unroll
      for (int j = 0; j < 4; ++j) {
        const int grow = row0 + wr + mi * 16 + l4 * 4 + j;
        const int gcol = col0 + wc + ni * 16 + l15;
        const float v = acc[mi][ni][j];
        if constexpr (MODE == GM_KV) {
          if (gcol < 1024) {
            Cb[((size_t)grow << 10) + gcol] = f2bf(v);
          } else {
            const int c = gcol - 1024;
            const int b = grow >> 10, ms = grow & 1023;
            const int h = c >> 7, d = c & 127;
            Cb2[((size_t)((b * 8 + h) * 128 + d) << 10) + ms] = f2bf(v);
          }
        }
      }
    }
  }
}

// ---------------- flash attention (double-buffered, KV-locality XCD remap) ----------------
__global__ __launch_bounds__(256, 2)
void attn2_k(const u16* __restrict__ Q, const u16* __restrict__ K,
             const u16* __restrict__ Vt, u16* __restrict__ O) {
  __shared__ u16 Ks[2][64 * 128];
  __shared__ u16 Vs[2][128 * 64];
  __shared__ u16 Plds[4][16 * 80];
  const int bid = blockIdx.x;                 // grid = 1024
  const int lb = (bid & 7) * 128 + (bid >> 3);
  const int bh = lb >> 4;
  const int mtile = lb & 15;
  const int b = bh >> 3, h = bh & 7;
  const int tid = threadIdx.x, lane = tid & 63, w = tid >> 6;
  const int l15 = lane & 15, l4 = lane >> 4;

  short8 qf[4];
  {
    const int qrow = b * 1024 + mtile * 64 + w * 16 + l15;
    const u16* qb = Q + ((size_t)qrow << 10) + h * 128;
    #pragma unroll
    for (int kk = 0; kk < 4; ++kk)
      qf[kk] = *(const short8*)(qb + kk * 32 + l4 * 8);
  }

  f32x4 o[8];
  #pragma unroll
  for (int db = 0; db < 8; ++db) o[db] = (f32x4){0.f, 0.f, 0.f, 0.f};
  float mrow[4], lrow[4];
  #pragma unroll
  for (int j = 0; j < 4; ++j) { mrow[j] = -1e30f; lrow[j] = 0.f; }
  const float scale = 0.08838834764831845f;

  auto stageKV = [&](int kt, int half) {
    #pragma unroll
    for (int j = 0; j < 4; ++j) {
      const int c = (j * 4 + w) * 64 + lane;
      const int r = c >> 4;
      const int coff = (((c & 15) ^ (r & 7)) << 3);
      const u16* gp = K + ((size_t)(b * 1024 + kt * 64 + r) << 10) + h * 128 + coff;
      gload16(gp, (void*)(Ks[half] + (j * 4 + w) * 512));
    }
    #pragma unroll
    for (int j = 0; j < 4; ++j) {
      const int c = (j * 4 + w) * 64 + lane;
      const int r = c >> 3;
      const int coff = (((c & 7) ^ (r & 7)) << 3);
      const u16* gp = Vt + ((size_t)((b * 8 + h) * 128 + r) << 10) + kt * 64 + coff;
      gload16(gp, (void*)(Vs[half] + (j * 4 + w) * 512));
    }
  };

  stageKV(0, 0);
  for (int kt = 0; kt < 16; ++kt) {
    const int cur = kt & 1;
    asm volatile("s_waitcnt vmcnt(0)" ::: "memory");
    __builtin_amdgcn_s_barrier();
    if (kt + 1 < 16) stageKV(kt + 1, cur ^ 1);

    const u16* ks_ = Ks[cur];
    const u16* vs_ = Vs[cur];
    f32x4 s[4];
    #pragma unroll
    for (int cb = 0; cb < 4; ++cb) {
      s[cb] = (f32x4){0.f, 0.f, 0.f, 0.f};
      #pragma unroll
      for (int kk = 0; kk < 4; ++kk) {
        const int col = (kk * 32 + l4 * 8) ^ ((l15 & 7) << 3);
        short8 bK = *(const short8*)(ks_ + (cb * 16 + l15) * 128 + col);
        s[cb] = __builtin_amdgcn_mfma_f32_16x16x32_bf16(qf[kk], bK, s[cb], 0, 0, 0);
      }
    }
    #pragma unroll
    for (int cb = 0; cb < 4; ++cb) {
      s[cb][0] *= scale; s[cb][1] *= scale; s[cb][2] *= scale; s[cb][3] *= scale;
    }
    #pragma unroll
    for (int j = 0; j < 4; ++j) {
      float mx = fmaxf(fmaxf(s[0][j], s[1][j]), fmaxf(s[2][j], s[3][j]));
      #pragma unroll
      for (int off = 8; off >= 1; off >>= 1)
        mx = fmaxf(mx, __shfl_xor(mx, off, 64));
      const float mn = fmaxf(mrow[j], mx);
      const float fac = __expf(mrow[j] - mn);
      mrow[j] = mn;
      float rs = 0.f;
      #pragma unroll
      for (int cb = 0; cb < 4; ++cb) {
        const float p = __expf(s[cb][j] - mn);
        s[cb][j] = p;
        rs += p;
      }
      #pragma unroll
      for (int off = 8; off >= 1; off >>= 1)
        rs += __shfl_xor(rs, off, 64);
      lrow[j] = lrow[j] * fac + rs;
      #pragma unroll
      for (int db = 0; db < 8; ++db) o[db][j] *= fac;
    }
    u16* pl = Plds[w];
    #pragma unroll
    for (int cb = 0; cb < 4; ++cb)
      #pragma unroll
      for (int j = 0; j < 4; ++j)
        pl[(l4 * 4 + j) * 80 + cb * 16 + l15] = f2bf(s[cb][j]);
    asm volatile("s_waitcnt lgkmcnt(0)" ::: "memory");
    __builtin_amdgcn_sched_barrier(0);
    short8 ap[2];
    #pragma unroll
    for (int ks2 = 0; ks2 < 2; ++ks2)
      ap[ks2] = *(const short8*)(pl + l15 * 80 + ks2 * 32 + l4 * 8);
    #pragma unroll
    for (int db = 0; db < 8; ++db) {
      #pragma unroll
      for (int ks2 = 0; ks2 < 2; ++ks2) {
        const int col = (ks2 * 32 + l4 * 8) ^ ((l15 & 7) << 3);
        short8 bV = *(const short8*)(vs_ + (db * 16 + l15) * 64 + col);
        o[db] = __builtin_amdgcn_mfma_f32_16x16x32_bf16(ap[ks2], bV, o[db], 0, 0, 0);
      }
    }
  }
  #pragma unroll
  for (int db = 0; db < 8; ++db) {
    #pragma unroll
    for (int j = 0; j < 4; ++j) {
      const int grow = b * 1024 + mtile * 64 + w * 16 + l4 * 4 + j;
      const int gcol = h * 128 + db * 16 + l15;
      O[((size_t)grow << 10) + gcol] = f2bf(o[db][j] / lrow[j]);
    }
  }
}

// ---------------- launch ----------------

extern "C" void kernel_launch(void* const* d_in, const int* in_sizes, int n_in,
                              void* d_out, int out_size, void* d_ws, size_t ws_size,
                              hipStream_t stream) {
  const float* x1     = (const float*)d_in[0];
  const float* x2     = (const float*)d_in[1];
  const float* conv_w = (const float*)d_in[2];
  const float* conv_b = (const float*)d_in[3];
  const float* wq     = (const float*)d_in[4];
  const float* wk     = (const float*)d_in[5];
  const float* wv     = (const float*)d_in[6];
  const float* proj_w = (const float*)d_in[7];
  const float* proj_b = (const float*)d_in[8];
  float* out = (float*)d_out;

  char* ws = (char*)d_ws;
  size_t off = 0;
  auto alloc = [&](size_t bytes) -> void* {
    void* p = ws + off;
    off += (bytes + 255) & ~(size_t)255;
    return p;
  };
  u16* x1b  = (u16*)alloc(8192ULL * 1024 * 2);
  u16* in_t_pad = (u16*)alloc((9248ULL + 96) * 2048 * 2);
  const size_t pad_bytes = 9248ULL * 2048 * 2;
  u16* Wp   = (u16*)alloc(9ULL * 2097152 * 2);
  u16* wqb  = (u16*)alloc(1048576ULL * 2);
  u16* wkb  = (u16*)alloc(1048576ULL * 2);
  u16* wvb  = (u16*)alloc(1048576ULL * 2);
  u16* pjb  = (u16*)alloc(1048576ULL * 2);
  u16* xc   = (u16*)alloc(8192ULL * 1024 * 2);
  u16* Qb   = (u16*)alloc(8192ULL * 1024 * 2);
  u16* Kb   = (u16*)alloc(8192ULL * 1024 * 2);
  u16* Vtb  = (u16*)alloc(8192ULL * 1024 * 2);
  u16* Ob   = (u16*)alloc(8192ULL * 1024 * 2);
  float* pConv = (float*)Qb;   // split-K f32 partials alias Qb..Ob

  // prep
  (void)hipMemsetAsync(in_t_pad, 0, pad_bytes + 96ULL * 2048 * 2, stream);
  cast4_k<<<dim3(1024, 4), 256, 0, stream>>>(wq, wk, wv, proj_w, wqb, wkb, wvb, pjb);
  build_pad<<<dim3(32, 16, 8), 256, 0, stream>>>(x1, x2, in_t_pad, x1b);
  pack_wp<<<8192, 256, 0, stream>>>(conv_w, Wp);

  // conv: halo-reuse implicit GEMM, 256x256 block, wave tile 128x128, split-K x2
  conv9_k<<<256, 256, 0, stream>>>(in_t_pad, Wp, pConv);
  addc_k<<<dim3(16, 16, 8), 256, 0, stream>>>(pConv, conv_b, xc);
  // Q
  gemm3_k<GM_PLAIN><<<256, 512, 0, stream>>>(x1b, wqb, Qb, nullptr, nullptr, nullptr, 1024, 3);
  // fused K+V
  gemm5_k<GM_KV><<<512, 512, 0, stream>>>(xc, wkb, Kb, Vtb, 1024, 4);
  // attention (1D grid, KV-locality remap)
  attn2_k<<<1024, 256, 0, stream>>>(Qb, Kb, Vtb, Ob);
  // projection + bias + residual
  gemm3_k<GM_PROJ><<<256, 512, 0, stream>>>(Ob, pjb, nullptr, out, proj_b, x1, 1024, 3);
}